// Round 1
// baseline (3712.947 us; speedup 1.0000x reference)
//
#include <hip/hip_runtime.h>
#include <hip/hip_bf16.h>
#include <math.h>

// Problem constants (DeepseekV3 MLA prefill)
#define NHEADS 16
#define DQK 192
#define DVDIM 128
#define SEQ 2048
#define BATCH 2
#define MROWS 4096   // BATCH*SEQ
#define HDIM 2048
#define QLORA 1536
#define KVLORA 512
#define SCALING 0.07216878364870323f  // 192^-0.5

__device__ __forceinline__ float4 ld4(const float* p) {
    return *reinterpret_cast<const float4*>(p);
}

// ---------------- GEMM: C[M,N] = A[M,K] (row stride lda) @ W[N,K]^T ----------------
// 64x64 tile, BK=32, 256 threads, 4x4 micro-tile per thread.
#define BM 64
#define BN 64
#define BK 32

__global__ __launch_bounds__(256) void gemm_nt(const float* __restrict__ A, int lda,
                                               const float* __restrict__ W,
                                               float* __restrict__ C,
                                               int M, int N, int K) {
    __shared__ float As[BK][BM + 4];
    __shared__ float Ws[BK][BN + 4];
    const int tid = threadIdx.x;
    const int tx = tid & 15, ty = tid >> 4;
    const int bm = blockIdx.y * BM, bn = blockIdx.x * BN;
    float acc[4][4] = {};
    for (int k0 = 0; k0 < K; k0 += BK) {
        __syncthreads();
        // Stage A and W tiles, transposed into [k][m] layout for float4 frag reads.
        #pragma unroll
        for (int u = 0; u < 2; u++) {
            int fi = tid + u * 256;           // 0..511 -> 64 rows x 8 float4
            int row = fi >> 3, kq = (fi & 7) * 4;
            float4 va = ld4(A + (size_t)(bm + row) * lda + k0 + kq);
            As[kq + 0][row] = va.x; As[kq + 1][row] = va.y;
            As[kq + 2][row] = va.z; As[kq + 3][row] = va.w;
            float4 vw = ld4(W + (size_t)(bn + row) * K + k0 + kq);
            Ws[kq + 0][row] = vw.x; Ws[kq + 1][row] = vw.y;
            Ws[kq + 2][row] = vw.z; Ws[kq + 3][row] = vw.w;
        }
        __syncthreads();
        #pragma unroll
        for (int kk = 0; kk < BK; kk++) {
            float4 a = *(const float4*)&As[kk][ty * 4];
            float4 b = *(const float4*)&Ws[kk][tx * 4];
            float av[4] = {a.x, a.y, a.z, a.w};
            float bv[4] = {b.x, b.y, b.z, b.w};
            #pragma unroll
            for (int i = 0; i < 4; i++)
                #pragma unroll
                for (int j = 0; j < 4; j++)
                    acc[i][j] = fmaf(av[i], bv[j], acc[i][j]);
        }
    }
    #pragma unroll
    for (int i = 0; i < 4; i++) {
        float4 o = make_float4(acc[i][0], acc[i][1], acc[i][2], acc[i][3]);
        *(float4*)&C[(size_t)(bm + ty * 4 + i) * N + bn + tx * 4] = o;
    }
}

// ---------------- RMSNorm in place over ncols of each row (row stride = stride) ----
__global__ __launch_bounds__(256) void rmsnorm_ip(float* __restrict__ x,
                                                  const float* __restrict__ w,
                                                  int ncols, int stride) {
    float* xr = x + (size_t)blockIdx.x * stride;
    const int tid = threadIdx.x;
    float ss = 0.f;
    for (int c = tid * 4; c < ncols; c += 1024) {
        float4 v = ld4(xr + c);
        ss += v.x * v.x + v.y * v.y + v.z * v.z + v.w * v.w;
    }
    #pragma unroll
    for (int d = 32; d > 0; d >>= 1) ss += __shfl_down(ss, d);
    __shared__ float wsum[4];
    if ((tid & 63) == 0) wsum[tid >> 6] = ss;
    __syncthreads();
    float total = wsum[0] + wsum[1] + wsum[2] + wsum[3];
    float scale = 1.0f / sqrtf(total / (float)ncols + 1e-6f);
    for (int c = tid * 4; c < ncols; c += 1024) {
        float4 v = ld4(xr + c);
        v.x *= scale * w[c + 0]; v.y *= scale * w[c + 1];
        v.z *= scale * w[c + 2]; v.w *= scale * w[c + 3];
        *(float4*)(xr + c) = v;
    }
}

// ---------------- RoPE cos/sin table (SEQ x 64), fp32 mimicking jax math ----------
__global__ void rope_table(float* __restrict__ cost, float* __restrict__ sint) {
    int s = blockIdx.x, j = threadIdx.x;   // 64 threads
    int i = j & 31;
    float inv = 1.0f / powf(10000.0f, (float)i * (1.0f / 32.0f));
    float ang = (float)s * inv;
    cost[s * 64 + j] = cosf(ang);
    sint[s * 64 + j] = sinf(ang);
}

// ---------------- RoPE applied in place to q rope slice of each head -------------
__global__ __launch_bounds__(256) void rope_q(float* __restrict__ q,
                                              const float* __restrict__ cost,
                                              const float* __restrict__ sint) {
    int row = blockIdx.x;
    int s = row & (SEQ - 1);
    int tid = threadIdx.x;
    #pragma unroll
    for (int u = 0; u < 2; u++) {
        int e = tid + u * 256;          // 0..511 = 16 heads * 32 pairs
        int h = e >> 5, j = e & 31;
        float* base = q + (size_t)row * (NHEADS * DQK) + h * DQK + DVDIM;
        float x1 = base[j], x2 = base[j + 32];
        float c1 = cost[s * 64 + j],      s1 = sint[s * 64 + j];
        float c2 = cost[s * 64 + j + 32], s2 = sint[s * 64 + j + 32];
        base[j]      = x1 * c1 - x2 * s1;   // rotate_half: first half gets -x2
        base[j + 32] = x2 * c2 + x1 * s2;   // second half gets +x1
    }
}

// ---------------- RoPE applied in place to k_rope (cols 512..575 of kv_a) --------
__global__ __launch_bounds__(256) void rope_k(float* __restrict__ kva,
                                              const float* __restrict__ cost,
                                              const float* __restrict__ sint) {
    int idx = blockIdx.x * 256 + threadIdx.x;   // 4096 rows * 32 pairs
    int row = idx >> 5, j = idx & 31;
    int s = row & (SEQ - 1);
    float* base = kva + (size_t)row * (KVLORA + 64) + KVLORA;
    float x1 = base[j], x2 = base[j + 32];
    float c1 = cost[s * 64 + j],      s1 = sint[s * 64 + j];
    float c2 = cost[s * 64 + j + 32], s2 = sint[s * 64 + j + 32];
    base[j]      = x1 * c1 - x2 * s1;
    base[j + 32] = x2 * c2 + x1 * s2;
}

// ---------------- Flash attention (fp32, causal, online softmax) ------------------
// grid: (BATCH*NHEADS, SEQ/QT); block 256. Q tile 32 rows, K tile 32 cols.
// Thread (r = tid>>3, sub = tid&7): scores for row r cols sub*4..+3, then
// PV accumulate for row r out cols sub*16..+15.
#define QT 32
#define KT 32

__global__ __launch_bounds__(256) void flash_fp32(const float* __restrict__ q,
                                                  const float* __restrict__ kv,
                                                  const float* __restrict__ kva,
                                                  float* __restrict__ out) {
    __shared__ float Qs[QT][196];
    __shared__ float Ks[KT][196];
    __shared__ float Vs[KT][132];
    __shared__ float Ps[QT][36];
    const int bh = blockIdx.x;
    const int b = bh >> 4, h = bh & 15;
    const int q0 = blockIdx.y * QT;
    const int tid = threadIdx.x;
    const int r = tid >> 3, sub = tid & 7;
    const size_t rowbase = (size_t)b * SEQ;

    for (int i = tid; i < QT * 48; i += 256) {      // 32 rows x 48 float4
        int row = i / 48, c4 = (i % 48) * 4;
        *(float4*)&Qs[row][c4] = ld4(q + (rowbase + q0 + row) * (NHEADS * DQK) + h * DQK + c4);
    }
    float m = -3.0e38f, l = 0.f;
    float acc[16];
    #pragma unroll
    for (int i = 0; i < 16; i++) acc[i] = 0.f;

    const int kend = q0 + QT;
    for (int k0 = 0; k0 < kend; k0 += KT) {
        __syncthreads();
        for (int i = tid; i < KT * 32; i += 256) {  // k_nope: 32 x 128
            int row = i >> 5, c4 = (i & 31) * 4;
            *(float4*)&Ks[row][c4] = ld4(kv + (rowbase + k0 + row) * 4096 + h * 256 + c4);
        }
        for (int i = tid; i < KT * 16; i += 256) {  // k_rope: 32 x 64
            int row = i >> 4, c4 = (i & 15) * 4;
            *(float4*)&Ks[row][128 + c4] = ld4(kva + (rowbase + k0 + row) * (KVLORA + 64) + KVLORA + c4);
        }
        for (int i = tid; i < KT * 32; i += 256) {  // V: 32 x 128
            int row = i >> 5, c4 = (i & 31) * 4;
            *(float4*)&Vs[row][c4] = ld4(kv + (rowbase + k0 + row) * 4096 + h * 256 + 128 + c4);
        }
        __syncthreads();

        float sc[4] = {0.f, 0.f, 0.f, 0.f};
        for (int k = 0; k < DQK; k += 4) {
            float4 qa = *(const float4*)&Qs[r][k];
            #pragma unroll
            for (int j = 0; j < 4; j++) {
                float4 kb = *(const float4*)&Ks[sub * 4 + j][k];
                sc[j] += qa.x * kb.x + qa.y * kb.y + qa.z * kb.z + qa.w * kb.w;
            }
        }
        float tmax = -3.0e38f;
        #pragma unroll
        for (int j = 0; j < 4; j++) {
            int kg = k0 + sub * 4 + j;
            sc[j] = (kg <= q0 + r) ? sc[j] * SCALING : -3.0e38f;
            tmax = fmaxf(tmax, sc[j]);
        }
        #pragma unroll
        for (int d = 1; d < 8; d <<= 1) tmax = fmaxf(tmax, __shfl_xor(tmax, d));
        float mnew = fmaxf(m, tmax);
        float escale = expf(m - mnew);
        float p[4], psum = 0.f;
        #pragma unroll
        for (int j = 0; j < 4; j++) {
            p[j] = expf(sc[j] - mnew);
            psum += p[j];
            Ps[r][sub * 4 + j] = p[j];
        }
        #pragma unroll
        for (int d = 1; d < 8; d <<= 1) psum += __shfl_xor(psum, d);
        l = l * escale + psum;
        m = mnew;
        #pragma unroll
        for (int i = 0; i < 16; i++) acc[i] *= escale;
        __syncthreads();

        #pragma unroll 4
        for (int kk = 0; kk < KT; kk++) {
            float pv = Ps[r][kk];
            const float* vrow = &Vs[kk][sub * 16];
            #pragma unroll
            for (int i4 = 0; i4 < 4; i4++) {
                float4 vv = *(const float4*)&vrow[i4 * 4];
                acc[i4 * 4 + 0] = fmaf(pv, vv.x, acc[i4 * 4 + 0]);
                acc[i4 * 4 + 1] = fmaf(pv, vv.y, acc[i4 * 4 + 1]);
                acc[i4 * 4 + 2] = fmaf(pv, vv.z, acc[i4 * 4 + 2]);
                acc[i4 * 4 + 3] = fmaf(pv, vv.w, acc[i4 * 4 + 3]);
            }
        }
    }
    float inv = 1.0f / l;
    float* op = out + (rowbase + q0 + r) * (NHEADS * DVDIM) + h * DVDIM + sub * 16;
    #pragma unroll
    for (int i4 = 0; i4 < 4; i4++) {
        float4 o = make_float4(acc[i4 * 4 + 0] * inv, acc[i4 * 4 + 1] * inv,
                               acc[i4 * 4 + 2] * inv, acc[i4 * 4 + 3] * inv);
        *(float4*)&op[i4 * 4] = o;
    }
}

extern "C" void kernel_launch(void* const* d_in, const int* in_sizes, int n_in,
                              void* d_out, int out_size, void* d_ws, size_t ws_size,
                              hipStream_t stream) {
    const float* hidden   = (const float*)d_in[0];  // 4096 x 2048
    const float* q_a_w    = (const float*)d_in[1];  // 1536 x 2048
    const float* q_a_ln_w = (const float*)d_in[2];  // 1536
    const float* q_b_w    = (const float*)d_in[3];  // 3072 x 1536
    const float* kv_a_w   = (const float*)d_in[4];  // 576 x 2048
    const float* kv_a_ln_w= (const float*)d_in[5];  // 512
    const float* kv_b_w   = (const float*)d_in[6];  // 4096 x 512
    const float* o_w      = (const float*)d_in[7];  // 2048 x 2048
    float* out = (float*)d_out;                     // 4096 x 2048

    float* ws = (float*)d_ws;
    const size_t off_qa   = 0;                         // 4096*1536
    const size_t off_q    = off_qa   + (size_t)4096 * 1536;  // 4096*3072
    const size_t off_kva  = off_q    + (size_t)4096 * 3072;  // 4096*576
    const size_t off_kv   = off_kva  + (size_t)4096 * 576;   // 4096*4096
    const size_t off_attn = off_kv   + (size_t)4096 * 4096;  // 4096*2048
    const size_t off_cos  = off_attn + (size_t)4096 * 2048;  // 2048*64
    const size_t off_sin  = off_cos  + (size_t)2048 * 64;    // 2048*64
    float* qa   = ws + off_qa;
    float* qbuf = ws + off_q;
    float* kva  = ws + off_kva;
    float* kvb  = ws + off_kv;
    float* attn = ws + off_attn;
    float* cosb = ws + off_cos;
    float* sinb = ws + off_sin;

    // q_a = hidden @ q_a_w.T        (4096 x 1536, K=2048)
    gemm_nt<<<dim3(1536 / BN, MROWS / BM), 256, 0, stream>>>(hidden, HDIM, q_a_w, qa, MROWS, 1536, 2048);
    // kv_a = hidden @ kv_a_w.T      (4096 x 576, K=2048)
    gemm_nt<<<dim3(576 / BN, MROWS / BM), 256, 0, stream>>>(hidden, HDIM, kv_a_w, kva, MROWS, 576, 2048);
    // rmsnorm in place
    rmsnorm_ip<<<MROWS, 256, 0, stream>>>(qa, q_a_ln_w, QLORA, QLORA);
    rmsnorm_ip<<<MROWS, 256, 0, stream>>>(kva, kv_a_ln_w, KVLORA, KVLORA + 64);
    // rope table
    rope_table<<<SEQ, 64, 0, stream>>>(cosb, sinb);
    // q = norm(q_a) @ q_b_w.T       (4096 x 3072, K=1536)
    gemm_nt<<<dim3(3072 / BN, MROWS / BM), 256, 0, stream>>>(qa, QLORA, q_b_w, qbuf, MROWS, 3072, 1536);
    // kv = norm(c_kv) @ kv_b_w.T    (4096 x 4096, K=512)  A row stride 576
    gemm_nt<<<dim3(4096 / BN, MROWS / BM), 256, 0, stream>>>(kva, KVLORA + 64, kv_b_w, kvb, MROWS, 4096, 512);
    // rope in place
    rope_q<<<MROWS, 256, 0, stream>>>(qbuf, cosb, sinb);
    rope_k<<<(MROWS * 32) / 256, 256, 0, stream>>>(kva, cosb, sinb);
    // flash attention -> attn (4096 x 2048, head-major inner layout)
    flash_fp32<<<dim3(BATCH * NHEADS, SEQ / QT), 256, 0, stream>>>(qbuf, kvb, kva, attn);
    // out = attn @ o_w.T            (4096 x 2048, K=2048)
    gemm_nt<<<dim3(2048 / BN, MROWS / BM), 256, 0, stream>>>(attn, NHEADS * DVDIM, o_w, out, MROWS, 2048, 2048);
}

// Round 2
// 2244.944 us; speedup vs baseline: 1.6539x; 1.6539x over previous
//
#include <hip/hip_runtime.h>
#include <hip/hip_bf16.h>
#include <math.h>

// Problem constants (DeepseekV3 MLA prefill)
#define NHEADS 16
#define DQK 192
#define DVDIM 128
#define SEQ 2048
#define BATCH 2
#define MROWS 4096   // BATCH*SEQ
#define HDIM 2048
#define QLORA 1536
#define KVLORA 512
#define SCALING 0.07216878364870323f  // 192^-0.5

typedef __attribute__((ext_vector_type(8))) short short8;
typedef __attribute__((ext_vector_type(4))) float f32x4;

__device__ __forceinline__ float4 ld4(const float* p) {
    return *reinterpret_cast<const float4*>(p);
}

__device__ __forceinline__ unsigned short f2b(float x) {
    __hip_bfloat16 h = __float2bfloat16(x);   // RNE; compiler fuses pairs to v_cvt_pk_bf16_f32
    return __builtin_bit_cast(unsigned short, h);
}

// =====================================================================
// bf16-MFMA GEMM: C[M,N] (fp32) = A[M,K] (fp32, row stride lda) @ W[N,K]^T (fp32)
// 128x128 tile, BK=32, 256 threads = 4 waves (2x2), each wave 64x64 out.
// fp32 global -> convert bf16 in regs -> LDS -> mfma_f32_16x16x32_bf16.
// N need not be divisible by 128 (B-row clamp + store guard).
// =====================================================================
__global__ __launch_bounds__(256) void gemm_bf_mfma(const float* __restrict__ A, int lda,
                                                    const float* __restrict__ W,
                                                    float* __restrict__ C,
                                                    int M, int N, int K) {
    __shared__ unsigned short As[128 * 32];   // [row][k] row-major, 8KB
    __shared__ unsigned short Bs[128 * 32];   // [ncol][k] row-major, 8KB

    const int tid = threadIdx.x;
    const int bm = blockIdx.y * 128, bn = blockIdx.x * 128;
    const int w = tid >> 6, lane = tid & 63;
    const int wr = (w >> 1) * 64, wc = (w & 1) * 64;   // wave's 64x64 sub-tile
    const int fr = lane & 15, fq = lane >> 4;          // fragment row / k-group

    // staging coords: thread covers rows (tid>>2) and 64+(tid>>2), cols (tid&3)*8 .. +7
    const int srow = tid >> 2;
    const int scol = (tid & 3) * 8;

    f32x4 acc[4][4];
    #pragma unroll
    for (int m = 0; m < 4; m++)
        #pragma unroll
        for (int n = 0; n < 4; n++) acc[m][n] = (f32x4)0.0f;

    const int NT = K >> 5;   // K / 32

    // prefetch tile 0 into registers (fp32)
    float4 ra[4], rb[4];
    {
        const float* a0 = A + (size_t)(bm + srow) * lda + scol;
        const float* a1 = A + (size_t)(bm + srow + 64) * lda + scol;
        ra[0] = ld4(a0); ra[1] = ld4(a0 + 4);
        ra[2] = ld4(a1); ra[3] = ld4(a1 + 4);
        int g0 = bn + srow;       if (g0 >= N) g0 = N - 1;
        int g1 = bn + srow + 64;  if (g1 >= N) g1 = N - 1;
        const float* b0 = W + (size_t)g0 * K + scol;
        const float* b1 = W + (size_t)g1 * K + scol;
        rb[0] = ld4(b0); rb[1] = ld4(b0 + 4);
        rb[2] = ld4(b1); rb[3] = ld4(b1 + 4);
    }

    for (int t = 0; t < NT; t++) {
        __syncthreads();   // previous tile's compute done; LDS reusable
        // convert + stage
        {
            short8 pa0, pa1, pb0, pb1;
            float va[8] = {ra[0].x, ra[0].y, ra[0].z, ra[0].w, ra[1].x, ra[1].y, ra[1].z, ra[1].w};
            float vb[8] = {ra[2].x, ra[2].y, ra[2].z, ra[2].w, ra[3].x, ra[3].y, ra[3].z, ra[3].w};
            float wa[8] = {rb[0].x, rb[0].y, rb[0].z, rb[0].w, rb[1].x, rb[1].y, rb[1].z, rb[1].w};
            float wb[8] = {rb[2].x, rb[2].y, rb[2].z, rb[2].w, rb[3].x, rb[3].y, rb[3].z, rb[3].w};
            #pragma unroll
            for (int j = 0; j < 8; j++) {
                pa0[j] = (short)f2b(va[j]); pa1[j] = (short)f2b(vb[j]);
                pb0[j] = (short)f2b(wa[j]); pb1[j] = (short)f2b(wb[j]);
            }
            *(short8*)&As[srow * 32 + scol]        = pa0;
            *(short8*)&As[(srow + 64) * 32 + scol] = pa1;
            *(short8*)&Bs[srow * 32 + scol]        = pb0;
            *(short8*)&Bs[(srow + 64) * 32 + scol] = pb1;
        }
        __syncthreads();   // tile staged

        // prefetch next tile while computing this one
        if (t + 1 < NT) {
            const int k0 = (t + 1) << 5;
            const float* a0 = A + (size_t)(bm + srow) * lda + k0 + scol;
            const float* a1 = A + (size_t)(bm + srow + 64) * lda + k0 + scol;
            ra[0] = ld4(a0); ra[1] = ld4(a0 + 4);
            ra[2] = ld4(a1); ra[3] = ld4(a1 + 4);
            int g0 = bn + srow;       if (g0 >= N) g0 = N - 1;
            int g1 = bn + srow + 64;  if (g1 >= N) g1 = N - 1;
            const float* b0 = W + (size_t)g0 * K + k0 + scol;
            const float* b1 = W + (size_t)g1 * K + k0 + scol;
            rb[0] = ld4(b0); rb[1] = ld4(b0 + 4);
            rb[2] = ld4(b1); rb[3] = ld4(b1 + 4);
        }

        // compute: 8 ds_read_b128 + 16 MFMA per wave
        short8 af[4], bfr[4];
        #pragma unroll
        for (int m = 0; m < 4; m++)
            af[m] = *(const short8*)&As[(wr + m * 16 + fr) * 32 + fq * 8];
        #pragma unroll
        for (int n = 0; n < 4; n++)
            bfr[n] = *(const short8*)&Bs[(wc + n * 16 + fr) * 32 + fq * 8];
        #pragma unroll
        for (int m = 0; m < 4; m++)
            #pragma unroll
            for (int n = 0; n < 4; n++)
                acc[m][n] = __builtin_amdgcn_mfma_f32_16x16x32_bf16(af[m], bfr[n], acc[m][n], 0, 0, 0);
    }

    // epilogue: C/D layout col=lane&15, row=(lane>>4)*4+reg  [m89-verified]
    #pragma unroll
    for (int m = 0; m < 4; m++) {
        #pragma unroll
        for (int n = 0; n < 4; n++) {
            const int col = bn + wc + n * 16 + fr;
            if (col < N) {
                #pragma unroll
                for (int j = 0; j < 4; j++) {
                    const int row = bm + wr + m * 16 + fq * 4 + j;
                    C[(size_t)row * N + col] = acc[m][n][j];
                }
            }
        }
    }
}

// ---------------- RMSNorm in place over ncols of each row (row stride = stride) ----
__global__ __launch_bounds__(256) void rmsnorm_ip(float* __restrict__ x,
                                                  const float* __restrict__ w,
                                                  int ncols, int stride) {
    float* xr = x + (size_t)blockIdx.x * stride;
    const int tid = threadIdx.x;
    float ss = 0.f;
    for (int c = tid * 4; c < ncols; c += 1024) {
        float4 v = ld4(xr + c);
        ss += v.x * v.x + v.y * v.y + v.z * v.z + v.w * v.w;
    }
    #pragma unroll
    for (int d = 32; d > 0; d >>= 1) ss += __shfl_down(ss, d);
    __shared__ float wsum[4];
    if ((tid & 63) == 0) wsum[tid >> 6] = ss;
    __syncthreads();
    float total = wsum[0] + wsum[1] + wsum[2] + wsum[3];
    float scale = 1.0f / sqrtf(total / (float)ncols + 1e-6f);
    for (int c = tid * 4; c < ncols; c += 1024) {
        float4 v = ld4(xr + c);
        v.x *= scale * w[c + 0]; v.y *= scale * w[c + 1];
        v.z *= scale * w[c + 2]; v.w *= scale * w[c + 3];
        *(float4*)(xr + c) = v;
    }
}

// ---------------- RoPE cos/sin table (SEQ x 64), fp32 mimicking jax math ----------
__global__ void rope_table(float* __restrict__ cost, float* __restrict__ sint) {
    int s = blockIdx.x, j = threadIdx.x;   // 64 threads
    int i = j & 31;
    float inv = 1.0f / powf(10000.0f, (float)i * (1.0f / 32.0f));
    float ang = (float)s * inv;
    cost[s * 64 + j] = cosf(ang);
    sint[s * 64 + j] = sinf(ang);
}

// ---------------- RoPE applied in place to q rope slice of each head -------------
__global__ __launch_bounds__(256) void rope_q(float* __restrict__ q,
                                              const float* __restrict__ cost,
                                              const float* __restrict__ sint) {
    int row = blockIdx.x;
    int s = row & (SEQ - 1);
    int tid = threadIdx.x;
    #pragma unroll
    for (int u = 0; u < 2; u++) {
        int e = tid + u * 256;          // 0..511 = 16 heads * 32 pairs
        int h = e >> 5, j = e & 31;
        float* base = q + (size_t)row * (NHEADS * DQK) + h * DQK + DVDIM;
        float x1 = base[j], x2 = base[j + 32];
        float c1 = cost[s * 64 + j],      s1 = sint[s * 64 + j];
        float c2 = cost[s * 64 + j + 32], s2 = sint[s * 64 + j + 32];
        base[j]      = x1 * c1 - x2 * s1;   // rotate_half: first half gets -x2
        base[j + 32] = x2 * c2 + x1 * s2;   // second half gets +x1
    }
}

// ---------------- RoPE applied in place to k_rope (cols 512..575 of kv_a) --------
__global__ __launch_bounds__(256) void rope_k(float* __restrict__ kva,
                                              const float* __restrict__ cost,
                                              const float* __restrict__ sint) {
    int idx = blockIdx.x * 256 + threadIdx.x;   // 4096 rows * 32 pairs
    int row = idx >> 5, j = idx & 31;
    int s = row & (SEQ - 1);
    float* base = kva + (size_t)row * (KVLORA + 64) + KVLORA;
    float x1 = base[j], x2 = base[j + 32];
    float c1 = cost[s * 64 + j],      s1 = sint[s * 64 + j];
    float c2 = cost[s * 64 + j + 32], s2 = sint[s * 64 + j + 32];
    base[j]      = x1 * c1 - x2 * s1;
    base[j + 32] = x2 * c2 + x1 * s2;
}

// ---------------- Flash attention (fp32, causal, online softmax) ------------------
#define QT 32
#define KT 32

__global__ __launch_bounds__(256) void flash_fp32(const float* __restrict__ q,
                                                  const float* __restrict__ kv,
                                                  const float* __restrict__ kva,
                                                  float* __restrict__ out) {
    __shared__ float Qs[QT][196];
    __shared__ float Ks[KT][196];
    __shared__ float Vs[KT][132];
    __shared__ float Ps[QT][36];
    const int bh = blockIdx.x;
    const int b = bh >> 4, h = bh & 15;
    const int q0 = blockIdx.y * QT;
    const int tid = threadIdx.x;
    const int r = tid >> 3, sub = tid & 7;
    const size_t rowbase = (size_t)b * SEQ;

    for (int i = tid; i < QT * 48; i += 256) {      // 32 rows x 48 float4
        int row = i / 48, c4 = (i % 48) * 4;
        *(float4*)&Qs[row][c4] = ld4(q + (rowbase + q0 + row) * (NHEADS * DQK) + h * DQK + c4);
    }
    float m = -3.0e38f, l = 0.f;
    float acc[16];
    #pragma unroll
    for (int i = 0; i < 16; i++) acc[i] = 0.f;

    const int kend = q0 + QT;
    for (int k0 = 0; k0 < kend; k0 += KT) {
        __syncthreads();
        for (int i = tid; i < KT * 32; i += 256) {  // k_nope: 32 x 128
            int row = i >> 5, c4 = (i & 31) * 4;
            *(float4*)&Ks[row][c4] = ld4(kv + (rowbase + k0 + row) * 4096 + h * 256 + c4);
        }
        for (int i = tid; i < KT * 16; i += 256) {  // k_rope: 32 x 64
            int row = i >> 4, c4 = (i & 15) * 4;
            *(float4*)&Ks[row][128 + c4] = ld4(kva + (rowbase + k0 + row) * (KVLORA + 64) + KVLORA + c4);
        }
        for (int i = tid; i < KT * 32; i += 256) {  // V: 32 x 128
            int row = i >> 5, c4 = (i & 31) * 4;
            *(float4*)&Vs[row][c4] = ld4(kv + (rowbase + k0 + row) * 4096 + h * 256 + 128 + c4);
        }
        __syncthreads();

        float sc[4] = {0.f, 0.f, 0.f, 0.f};
        for (int k = 0; k < DQK; k += 4) {
            float4 qa = *(const float4*)&Qs[r][k];
            #pragma unroll
            for (int j = 0; j < 4; j++) {
                float4 kb = *(const float4*)&Ks[sub * 4 + j][k];
                sc[j] += qa.x * kb.x + qa.y * kb.y + qa.z * kb.z + qa.w * kb.w;
            }
        }
        float tmax = -3.0e38f;
        #pragma unroll
        for (int j = 0; j < 4; j++) {
            int kg = k0 + sub * 4 + j;
            sc[j] = (kg <= q0 + r) ? sc[j] * SCALING : -3.0e38f;
            tmax = fmaxf(tmax, sc[j]);
        }
        #pragma unroll
        for (int d = 1; d < 8; d <<= 1) tmax = fmaxf(tmax, __shfl_xor(tmax, d));
        float mnew = fmaxf(m, tmax);
        float escale = expf(m - mnew);
        float p[4], psum = 0.f;
        #pragma unroll
        for (int j = 0; j < 4; j++) {
            p[j] = expf(sc[j] - mnew);
            psum += p[j];
            Ps[r][sub * 4 + j] = p[j];
        }
        #pragma unroll
        for (int d = 1; d < 8; d <<= 1) psum += __shfl_xor(psum, d);
        l = l * escale + psum;
        m = mnew;
        #pragma unroll
        for (int i = 0; i < 16; i++) acc[i] *= escale;
        __syncthreads();

        #pragma unroll 4
        for (int kk = 0; kk < KT; kk++) {
            float pv = Ps[r][kk];
            const float* vrow = &Vs[kk][sub * 16];
            #pragma unroll
            for (int i4 = 0; i4 < 4; i4++) {
                float4 vv = *(const float4*)&vrow[i4 * 4];
                acc[i4 * 4 + 0] = fmaf(pv, vv.x, acc[i4 * 4 + 0]);
                acc[i4 * 4 + 1] = fmaf(pv, vv.y, acc[i4 * 4 + 1]);
                acc[i4 * 4 + 2] = fmaf(pv, vv.z, acc[i4 * 4 + 2]);
                acc[i4 * 4 + 3] = fmaf(pv, vv.w, acc[i4 * 4 + 3]);
            }
        }
    }
    float inv = 1.0f / l;
    float* op = out + (rowbase + q0 + r) * (NHEADS * DVDIM) + h * DVDIM + sub * 16;
    #pragma unroll
    for (int i4 = 0; i4 < 4; i4++) {
        float4 o = make_float4(acc[i4 * 4 + 0] * inv, acc[i4 * 4 + 1] * inv,
                               acc[i4 * 4 + 2] * inv, acc[i4 * 4 + 3] * inv);
        *(float4*)&op[i4 * 4] = o;
    }
}

extern "C" void kernel_launch(void* const* d_in, const int* in_sizes, int n_in,
                              void* d_out, int out_size, void* d_ws, size_t ws_size,
                              hipStream_t stream) {
    const float* hidden   = (const float*)d_in[0];  // 4096 x 2048
    const float* q_a_w    = (const float*)d_in[1];  // 1536 x 2048
    const float* q_a_ln_w = (const float*)d_in[2];  // 1536
    const float* q_b_w    = (const float*)d_in[3];  // 3072 x 1536
    const float* kv_a_w   = (const float*)d_in[4];  // 576 x 2048
    const float* kv_a_ln_w= (const float*)d_in[5];  // 512
    const float* kv_b_w   = (const float*)d_in[6];  // 4096 x 512
    const float* o_w      = (const float*)d_in[7];  // 2048 x 2048
    float* out = (float*)d_out;                     // 4096 x 2048

    float* ws = (float*)d_ws;
    const size_t off_qa   = 0;                         // 4096*1536
    const size_t off_q    = off_qa   + (size_t)4096 * 1536;  // 4096*3072
    const size_t off_kva  = off_q    + (size_t)4096 * 3072;  // 4096*576
    const size_t off_kv   = off_kva  + (size_t)4096 * 576;   // 4096*4096
    const size_t off_attn = off_kv   + (size_t)4096 * 4096;  // 4096*2048
    const size_t off_cos  = off_attn + (size_t)4096 * 2048;  // 2048*64
    const size_t off_sin  = off_cos  + (size_t)2048 * 64;    // 2048*64
    float* qa   = ws + off_qa;
    float* qbuf = ws + off_q;
    float* kva  = ws + off_kva;
    float* kvb  = ws + off_kv;
    float* attn = ws + off_attn;
    float* cosb = ws + off_cos;
    float* sinb = ws + off_sin;

    // q_a = hidden @ q_a_w.T        (4096 x 1536, K=2048)
    gemm_bf_mfma<<<dim3(1536 / 128, MROWS / 128), 256, 0, stream>>>(hidden, HDIM, q_a_w, qa, MROWS, 1536, 2048);
    // kv_a = hidden @ kv_a_w.T      (4096 x 576, K=2048) -- N not divisible by 128, guarded
    gemm_bf_mfma<<<dim3((576 + 127) / 128, MROWS / 128), 256, 0, stream>>>(hidden, HDIM, kv_a_w, kva, MROWS, 576, 2048);
    // rmsnorm in place
    rmsnorm_ip<<<MROWS, 256, 0, stream>>>(qa, q_a_ln_w, QLORA, QLORA);
    rmsnorm_ip<<<MROWS, 256, 0, stream>>>(kva, kv_a_ln_w, KVLORA, KVLORA + 64);
    // rope table
    rope_table<<<SEQ, 64, 0, stream>>>(cosb, sinb);
    // q = norm(q_a) @ q_b_w.T       (4096 x 3072, K=1536)
    gemm_bf_mfma<<<dim3(3072 / 128, MROWS / 128), 256, 0, stream>>>(qa, QLORA, q_b_w, qbuf, MROWS, 3072, 1536);
    // kv = norm(c_kv) @ kv_b_w.T    (4096 x 4096, K=512)  A row stride 576
    gemm_bf_mfma<<<dim3(4096 / 128, MROWS / 128), 256, 0, stream>>>(kva, KVLORA + 64, kv_b_w, kvb, MROWS, 4096, 512);
    // rope in place
    rope_q<<<MROWS, 256, 0, stream>>>(qbuf, cosb, sinb);
    rope_k<<<(MROWS * 32) / 256, 256, 0, stream>>>(kva, cosb, sinb);
    // flash attention -> attn (4096 x 2048, head-major inner layout)
    flash_fp32<<<dim3(BATCH * NHEADS, SEQ / QT), 256, 0, stream>>>(qbuf, kvb, kva, attn);
    // out = attn @ o_w.T            (4096 x 2048, K=2048)
    gemm_bf_mfma<<<dim3(2048 / 128, MROWS / 128), 256, 0, stream>>>(attn, NHEADS * DVDIM, o_w, out, MROWS, 2048, 2048);
}

// Round 3
// 821.175 us; speedup vs baseline: 4.5215x; 2.7338x over previous
//
#include <hip/hip_runtime.h>
#include <hip/hip_bf16.h>
#include <math.h>

// Problem constants (DeepseekV3 MLA prefill)
#define NHEADS 16
#define DQK 192
#define DVDIM 128
#define SEQ 2048
#define BATCH 2
#define MROWS 4096   // BATCH*SEQ
#define HDIM 2048
#define QLORA 1536
#define KVLORA 512
#define SCALING 0.07216878364870323f  // 192^-0.5

typedef __attribute__((ext_vector_type(8))) short short8;
typedef __attribute__((ext_vector_type(4))) float f32x4;

__device__ __forceinline__ float4 ld4(const float* p) {
    return *reinterpret_cast<const float4*>(p);
}

__device__ __forceinline__ unsigned short f2b(float x) {
    __hip_bfloat16 h = __float2bfloat16(x);   // RNE
    return __builtin_bit_cast(unsigned short, h);
}

// =====================================================================
// bf16-MFMA GEMM: C[M,N] (fp32) = A[M,K] (fp32, row stride lda) @ W[N,K]^T
// 128x128 tile, BK=32, 256 threads = 4 waves (2x2), each wave 64x64 out.
// =====================================================================
__global__ __launch_bounds__(256) void gemm_bf_mfma(const float* __restrict__ A, int lda,
                                                    const float* __restrict__ W,
                                                    float* __restrict__ C,
                                                    int M, int N, int K) {
    __shared__ unsigned short As[128 * 32];   // [row][k] row-major, 8KB
    __shared__ unsigned short Bs[128 * 32];   // [ncol][k] row-major, 8KB

    const int tid = threadIdx.x;
    const int bm = blockIdx.y * 128, bn = blockIdx.x * 128;
    const int w = tid >> 6, lane = tid & 63;
    const int wr = (w >> 1) * 64, wc = (w & 1) * 64;
    const int fr = lane & 15, fq = lane >> 4;

    const int srow = tid >> 2;
    const int scol = (tid & 3) * 8;

    f32x4 acc[4][4];
    #pragma unroll
    for (int m = 0; m < 4; m++)
        #pragma unroll
        for (int n = 0; n < 4; n++) acc[m][n] = (f32x4)0.0f;

    const int NT = K >> 5;

    float4 ra[4], rb[4];
    {
        const float* a0 = A + (size_t)(bm + srow) * lda + scol;
        const float* a1 = A + (size_t)(bm + srow + 64) * lda + scol;
        ra[0] = ld4(a0); ra[1] = ld4(a0 + 4);
        ra[2] = ld4(a1); ra[3] = ld4(a1 + 4);
        int g0 = bn + srow;       if (g0 >= N) g0 = N - 1;
        int g1 = bn + srow + 64;  if (g1 >= N) g1 = N - 1;
        const float* b0 = W + (size_t)g0 * K + scol;
        const float* b1 = W + (size_t)g1 * K + scol;
        rb[0] = ld4(b0); rb[1] = ld4(b0 + 4);
        rb[2] = ld4(b1); rb[3] = ld4(b1 + 4);
    }

    for (int t = 0; t < NT; t++) {
        __syncthreads();
        {
            short8 pa0, pa1, pb0, pb1;
            float va[8] = {ra[0].x, ra[0].y, ra[0].z, ra[0].w, ra[1].x, ra[1].y, ra[1].z, ra[1].w};
            float vb[8] = {ra[2].x, ra[2].y, ra[2].z, ra[2].w, ra[3].x, ra[3].y, ra[3].z, ra[3].w};
            float wa[8] = {rb[0].x, rb[0].y, rb[0].z, rb[0].w, rb[1].x, rb[1].y, rb[1].z, rb[1].w};
            float wb[8] = {rb[2].x, rb[2].y, rb[2].z, rb[2].w, rb[3].x, rb[3].y, rb[3].z, rb[3].w};
            #pragma unroll
            for (int j = 0; j < 8; j++) {
                pa0[j] = (short)f2b(va[j]); pa1[j] = (short)f2b(vb[j]);
                pb0[j] = (short)f2b(wa[j]); pb1[j] = (short)f2b(wb[j]);
            }
            *(short8*)&As[srow * 32 + scol]        = pa0;
            *(short8*)&As[(srow + 64) * 32 + scol] = pa1;
            *(short8*)&Bs[srow * 32 + scol]        = pb0;
            *(short8*)&Bs[(srow + 64) * 32 + scol] = pb1;
        }
        __syncthreads();

        if (t + 1 < NT) {
            const int k0 = (t + 1) << 5;
            const float* a0 = A + (size_t)(bm + srow) * lda + k0 + scol;
            const float* a1 = A + (size_t)(bm + srow + 64) * lda + k0 + scol;
            ra[0] = ld4(a0); ra[1] = ld4(a0 + 4);
            ra[2] = ld4(a1); ra[3] = ld4(a1 + 4);
            int g0 = bn + srow;       if (g0 >= N) g0 = N - 1;
            int g1 = bn + srow + 64;  if (g1 >= N) g1 = N - 1;
            const float* b0 = W + (size_t)g0 * K + k0 + scol;
            const float* b1 = W + (size_t)g1 * K + k0 + scol;
            rb[0] = ld4(b0); rb[1] = ld4(b0 + 4);
            rb[2] = ld4(b1); rb[3] = ld4(b1 + 4);
        }

        short8 af[4], bfr[4];
        #pragma unroll
        for (int m = 0; m < 4; m++)
            af[m] = *(const short8*)&As[(wr + m * 16 + fr) * 32 + fq * 8];
        #pragma unroll
        for (int n = 0; n < 4; n++)
            bfr[n] = *(const short8*)&Bs[(wc + n * 16 + fr) * 32 + fq * 8];
        #pragma unroll
        for (int m = 0; m < 4; m++)
            #pragma unroll
            for (int n = 0; n < 4; n++)
                acc[m][n] = __builtin_amdgcn_mfma_f32_16x16x32_bf16(af[m], bfr[n], acc[m][n], 0, 0, 0);
    }

    #pragma unroll
    for (int m = 0; m < 4; m++) {
        #pragma unroll
        for (int n = 0; n < 4; n++) {
            const int col = bn + wc + n * 16 + fr;
            if (col < N) {
                #pragma unroll
                for (int j = 0; j < 4; j++) {
                    const int row = bm + wr + m * 16 + fq * 4 + j;
                    C[(size_t)row * N + col] = acc[m][n][j];
                }
            }
        }
    }
}

// ---------------- RMSNorm in place ----------------
__global__ __launch_bounds__(256) void rmsnorm_ip(float* __restrict__ x,
                                                  const float* __restrict__ w,
                                                  int ncols, int stride) {
    float* xr = x + (size_t)blockIdx.x * stride;
    const int tid = threadIdx.x;
    float ss = 0.f;
    for (int c = tid * 4; c < ncols; c += 1024) {
        float4 v = ld4(xr + c);
        ss += v.x * v.x + v.y * v.y + v.z * v.z + v.w * v.w;
    }
    #pragma unroll
    for (int d = 32; d > 0; d >>= 1) ss += __shfl_down(ss, d);
    __shared__ float wsum[4];
    if ((tid & 63) == 0) wsum[tid >> 6] = ss;
    __syncthreads();
    float total = wsum[0] + wsum[1] + wsum[2] + wsum[3];
    float scale = 1.0f / sqrtf(total / (float)ncols + 1e-6f);
    for (int c = tid * 4; c < ncols; c += 1024) {
        float4 v = ld4(xr + c);
        v.x *= scale * w[c + 0]; v.y *= scale * w[c + 1];
        v.z *= scale * w[c + 2]; v.w *= scale * w[c + 3];
        *(float4*)(xr + c) = v;
    }
}

// ---------------- RoPE cos/sin table (SEQ x 64) ----------
__global__ void rope_table(float* __restrict__ cost, float* __restrict__ sint) {
    int s = blockIdx.x, j = threadIdx.x;
    int i = j & 31;
    float inv = 1.0f / powf(10000.0f, (float)i * (1.0f / 32.0f));
    float ang = (float)s * inv;
    cost[s * 64 + j] = cosf(ang);
    sint[s * 64 + j] = sinf(ang);
}

// ---------------- RoPE k_rope in place (cols 512..575 of kv_a) --------
__global__ __launch_bounds__(256) void rope_k(float* __restrict__ kva,
                                              const float* __restrict__ cost,
                                              const float* __restrict__ sint) {
    int idx = blockIdx.x * 256 + threadIdx.x;
    int row = idx >> 5, j = idx & 31;
    int s = row & (SEQ - 1);
    float* base = kva + (size_t)row * (KVLORA + 64) + KVLORA;
    float x1 = base[j], x2 = base[j + 32];
    float c1 = cost[s * 64 + j],      s1 = sint[s * 64 + j];
    float c2 = cost[s * 64 + j + 32], s2 = sint[s * 64 + j + 32];
    base[j]      = x1 * c1 - x2 * s1;
    base[j + 32] = x2 * c2 + x1 * s2;
}

// ---------------- q convert: fp32 qbuf[4096][3072] -> bf16 qbf[b][h][s][192], rope fused
__global__ __launch_bounds__(256) void rope_q_cvt(const float* __restrict__ qbuf,
                                                  const float* __restrict__ cost,
                                                  const float* __restrict__ sint,
                                                  unsigned short* __restrict__ qbf) {
    const int r = blockIdx.x;            // 0..4095 (b*2048+s)
    const int b = r >> 11, s = r & (SEQ - 1);
    const float* in = qbuf + (size_t)r * 3072;
    for (int i = threadIdx.x; i < 3072; i += 256) {
        const int h = i / DQK, d = i % DQK;
        float val;
        if (d < DVDIM) {
            val = in[h * DQK + d];
        } else {
            const int j = d - DVDIM;
            const float x  = in[h * DQK + DVDIM + j];
            const float rot = (j < 32) ? -in[h * DQK + DVDIM + j + 32]
                                       :  in[h * DQK + DVDIM + j - 32];
            val = x * cost[s * 64 + j] + rot * sint[s * 64 + j];
        }
        qbf[(((size_t)(b * NHEADS + h)) * SEQ + s) * DQK + d] = f2b(val);
    }
}

// ---------------- k convert: kvb k_nope + kva k_rope -> bf16 kbf[b][h][s][192]
__global__ __launch_bounds__(256) void kv_cvt_k(const float* __restrict__ kvb,
                                                const float* __restrict__ kva,
                                                unsigned short* __restrict__ kbf) {
    const int bh = blockIdx.x, st = blockIdx.y;   // bh 0..31, st 0..15 (128 s each)
    const int b = bh >> 4, h = bh & 15;
    const int s0 = st * 128;
    for (int i = threadIdx.x; i < 128 * DQK; i += 256) {
        const int si = i / DQK, d = i % DQK;
        const int r = b * SEQ + s0 + si;
        float val = (d < DVDIM) ? kvb[(size_t)r * 4096 + h * 256 + d]
                                : kva[(size_t)r * (KVLORA + 64) + KVLORA + (d - DVDIM)];
        kbf[(((size_t)bh) * SEQ + s0 + si) * DQK + d] = f2b(val);
    }
}

// ---------------- v convert + transpose: kvb v -> bf16 vbfT[b][h][128][2048]
__global__ __launch_bounds__(256) void kv_cvt_v(const float* __restrict__ kvb,
                                                unsigned short* __restrict__ vbfT) {
    __shared__ unsigned short Vt[64][136];
    const int bh = blockIdx.x, st = blockIdx.y;   // st 0..31 (64 s each)
    const int b = bh >> 4, h = bh & 15;
    const int s0 = st * 64;
    for (int i = threadIdx.x; i < 64 * 128; i += 256) {
        const int si = i >> 7, d = i & 127;
        Vt[si][d] = f2b(kvb[(size_t)(b * SEQ + s0 + si) * 4096 + h * 256 + 128 + d]);
    }
    __syncthreads();
    for (int i = threadIdx.x; i < 128 * 64; i += 256) {
        const int dv = i >> 6, sc = i & 63;
        vbfT[(((size_t)bh) * 128 + dv) * SEQ + s0 + sc] = Vt[sc][dv];
    }
}

// =====================================================================
// bf16-MFMA flash attention (causal, online softmax, fp32 accum)
// Block: 256 thr = 4 waves, 64 q rows (16/wave). KV tile 64.
// Q frags in regs; K, V^T staged in padded LDS; P via wave-private LDS.
// =====================================================================
__global__ __launch_bounds__(256) void flash_mfma(const unsigned short* __restrict__ qbf,
                                                  const unsigned short* __restrict__ kbf,
                                                  const unsigned short* __restrict__ vbfT,
                                                  float* __restrict__ attn) {
    __shared__ unsigned short Ks[64][200];   // [kv][k=192], +8 pad
    __shared__ unsigned short Vs[128][72];   // [dv][kv=64], +8 pad
    __shared__ unsigned short Ps[4][16][72]; // per-wave P [q=16][kv=64], +8 pad

    const int qt = blockIdx.x, bh = blockIdx.y;
    const int b = bh >> 4, h = bh & 15;
    const int q0 = qt * 64;
    const int tid = threadIdx.x;
    const int w = tid >> 6, lane = tid & 63;
    const int fr = lane & 15, fq = lane >> 4;

    const unsigned short* Qh = qbf + ((size_t)bh * SEQ) * DQK;
    const unsigned short* Kh = kbf + ((size_t)bh * SEQ) * DQK;
    const unsigned short* Vh = vbfT + ((size_t)bh * 128) * SEQ;

    // Q fragments for this wave's 16 rows: 6 k-windows of 32
    short8 qf[6];
    {
        const unsigned short* qrow = Qh + (size_t)(q0 + w * 16 + fr) * DQK;
        #pragma unroll
        for (int kw = 0; kw < 6; kw++)
            qf[kw] = *(const short8*)(qrow + kw * 32 + fq * 8);
    }

    f32x4 acc[8];
    #pragma unroll
    for (int n = 0; n < 8; n++) acc[n] = (f32x4)0.0f;
    float mrow[4], lrow[4];
    #pragma unroll
    for (int j = 0; j < 4; j++) { mrow[j] = -3.0e38f; lrow[j] = 0.0f; }

    const int ntiles = qt + 1;
    for (int t = 0; t < ntiles; t++) {
        const int kt0 = t * 64;
        __syncthreads();   // previous tile's LDS reads complete
        // stage K tile: 64 x 192
        #pragma unroll
        for (int u = 0; u < 6; u++) {
            int i = tid + u * 256;              // 1536 chunks of 8
            int row = i / 24, c = (i % 24) * 8;
            *(short8*)&Ks[row][c] = *(const short8*)(Kh + (size_t)(kt0 + row) * DQK + c);
        }
        // stage V^T tile: 128 x 64
        #pragma unroll
        for (int u = 0; u < 4; u++) {
            int i = tid + u * 256;              // 1024 chunks
            int row = i >> 3, c = (i & 7) * 8;
            *(short8*)&Vs[row][c] = *(const short8*)(Vh + (size_t)row * SEQ + kt0 + c);
        }
        __syncthreads();

        // S = Q K^T  (wave rows 16 x kv 64)
        f32x4 sfr[4];
        #pragma unroll
        for (int n = 0; n < 4; n++) sfr[n] = (f32x4)0.0f;
        #pragma unroll
        for (int kw = 0; kw < 6; kw++) {
            #pragma unroll
            for (int n = 0; n < 4; n++) {
                short8 kf = *(const short8*)&Ks[n * 16 + fr][kw * 32 + fq * 8];
                sfr[n] = __builtin_amdgcn_mfma_f32_16x16x32_bf16(qf[kw], kf, sfr[n], 0, 0, 0);
            }
        }

        // online softmax (per q row = fq*4+j, kv across n tiles x fr lanes)
        const bool diag = (t == qt);
        float pv[4][4];   // [n][j] stash of scaled/masked scores
        float mnew[4];
        #pragma unroll
        for (int j = 0; j < 4; j++) mnew[j] = mrow[j];
        #pragma unroll
        for (int n = 0; n < 4; n++) {
            #pragma unroll
            for (int j = 0; j < 4; j++) {
                float s = sfr[n][j] * SCALING;
                if (diag && (n * 16 + fr > w * 16 + fq * 4 + j)) s = -3.0e38f;
                pv[n][j] = s;
                mnew[j] = fmaxf(mnew[j], s);
            }
        }
        #pragma unroll
        for (int j = 0; j < 4; j++) {
            mnew[j] = fmaxf(mnew[j], __shfl_xor(mnew[j], 1));
            mnew[j] = fmaxf(mnew[j], __shfl_xor(mnew[j], 2));
            mnew[j] = fmaxf(mnew[j], __shfl_xor(mnew[j], 4));
            mnew[j] = fmaxf(mnew[j], __shfl_xor(mnew[j], 8));
        }
        float es[4], psum[4];
        #pragma unroll
        for (int j = 0; j < 4; j++) {
            es[j] = __expf(mrow[j] - mnew[j]);
            psum[j] = 0.0f;
        }
        #pragma unroll
        for (int n = 0; n < 4; n++) {
            #pragma unroll
            for (int j = 0; j < 4; j++) {
                float p = __expf(pv[n][j] - mnew[j]);
                pv[n][j] = p;
                psum[j] += p;
            }
        }
        #pragma unroll
        for (int j = 0; j < 4; j++) {
            psum[j] += __shfl_xor(psum[j], 1);
            psum[j] += __shfl_xor(psum[j], 2);
            psum[j] += __shfl_xor(psum[j], 4);
            psum[j] += __shfl_xor(psum[j], 8);
            lrow[j] = lrow[j] * es[j] + psum[j];
            mrow[j] = mnew[j];
        }
        #pragma unroll
        for (int n = 0; n < 8; n++) {
            #pragma unroll
            for (int j = 0; j < 4; j++) acc[n][j] *= es[j];
        }
        // write P (bf16) to wave-private LDS
        #pragma unroll
        for (int n = 0; n < 4; n++) {
            #pragma unroll
            for (int j = 0; j < 4; j++)
                Ps[w][fq * 4 + j][n * 16 + fr] = f2b(pv[n][j]);
        }
        // PV: O += P V   (A frag from Ps, B frag from Vs = V^T)
        #pragma unroll
        for (int tt = 0; tt < 2; tt++) {
            short8 pa = *(const short8*)&Ps[w][fr][tt * 32 + fq * 8];
            #pragma unroll
            for (int n = 0; n < 8; n++) {
                short8 vf = *(const short8*)&Vs[n * 16 + fr][tt * 32 + fq * 8];
                acc[n] = __builtin_amdgcn_mfma_f32_16x16x32_bf16(pa, vf, acc[n], 0, 0, 0);
            }
        }
    }

    // epilogue: normalize and store (attn row = b*2048 + q, col = h*128 + dv)
    #pragma unroll
    for (int j = 0; j < 4; j++) {
        const float inv = 1.0f / lrow[j];
        float* orow = attn + (size_t)(b * SEQ + q0 + w * 16 + fq * 4 + j) * (NHEADS * DVDIM) + h * DVDIM;
        #pragma unroll
        for (int n = 0; n < 8; n++)
            orow[n * 16 + fr] = acc[n][j] * inv;
    }
}

extern "C" void kernel_launch(void* const* d_in, const int* in_sizes, int n_in,
                              void* d_out, int out_size, void* d_ws, size_t ws_size,
                              hipStream_t stream) {
    const float* hidden   = (const float*)d_in[0];
    const float* q_a_w    = (const float*)d_in[1];
    const float* q_a_ln_w = (const float*)d_in[2];
    const float* q_b_w    = (const float*)d_in[3];
    const float* kv_a_w   = (const float*)d_in[4];
    const float* kv_a_ln_w= (const float*)d_in[5];
    const float* kv_b_w   = (const float*)d_in[6];
    const float* o_w      = (const float*)d_in[7];
    float* out = (float*)d_out;

    float* ws = (float*)d_ws;
    const size_t off_qa   = 0;                               // 4096*1536 f32
    const size_t off_q    = off_qa   + (size_t)4096 * 1536;  // 4096*3072 f32
    const size_t off_kva  = off_q    + (size_t)4096 * 3072;  // 4096*576  f32
    const size_t off_kv   = off_kva  + (size_t)4096 * 576;   // 4096*4096 f32
    const size_t off_attn = off_kv   + (size_t)4096 * 4096;  // 4096*2048 f32
    const size_t off_cos  = off_attn + (size_t)4096 * 2048;
    const size_t off_sin  = off_cos  + (size_t)2048 * 64;
    float* qa   = ws + off_qa;
    float* qbuf = ws + off_q;
    float* kva  = ws + off_kva;
    float* kvb  = ws + off_kv;
    float* attn = ws + off_attn;
    float* cosb = ws + off_cos;
    float* sinb = ws + off_sin;

    // bf16 overlays on dead fp32 buffers:
    unsigned short* qbf  = (unsigned short*)qa;    // 2*16*2048*192 = 12.58M shorts (25.2MB <= qa 25.2MB)
    unsigned short* kbf  = (unsigned short*)qbuf;  // 12.58M shorts
    unsigned short* vbfT = (unsigned short*)qbuf + (size_t)2 * 16 * 2048 * 192;  // 8.39M shorts (total 41.9MB <= qbuf 50.3MB)

    // q_a = hidden @ q_a_w.T
    gemm_bf_mfma<<<dim3(1536 / 128, MROWS / 128), 256, 0, stream>>>(hidden, HDIM, q_a_w, qa, MROWS, 1536, 2048);
    // kv_a = hidden @ kv_a_w.T
    gemm_bf_mfma<<<dim3((576 + 127) / 128, MROWS / 128), 256, 0, stream>>>(hidden, HDIM, kv_a_w, kva, MROWS, 576, 2048);
    rmsnorm_ip<<<MROWS, 256, 0, stream>>>(qa, q_a_ln_w, QLORA, QLORA);
    rmsnorm_ip<<<MROWS, 256, 0, stream>>>(kva, kv_a_ln_w, KVLORA, KVLORA + 64);
    rope_table<<<SEQ, 64, 0, stream>>>(cosb, sinb);
    // q = norm(q_a) @ q_b_w.T
    gemm_bf_mfma<<<dim3(3072 / 128, MROWS / 128), 256, 0, stream>>>(qa, QLORA, q_b_w, qbuf, MROWS, 3072, 1536);
    // kv = norm(c_kv) @ kv_b_w.T
    gemm_bf_mfma<<<dim3(4096 / 128, MROWS / 128), 256, 0, stream>>>(kva, KVLORA + 64, kv_b_w, kvb, MROWS, 4096, 512);
    // rope k in place, then converters (qa dead after q_b gemm; qbuf dead after rope_q_cvt)
    rope_k<<<(MROWS * 32) / 256, 256, 0, stream>>>(kva, cosb, sinb);
    rope_q_cvt<<<MROWS, 256, 0, stream>>>(qbuf, cosb, sinb, qbf);
    kv_cvt_k<<<dim3(32, 16), 256, 0, stream>>>(kvb, kva, kbf);
    kv_cvt_v<<<dim3(32, 32), 256, 0, stream>>>(kvb, vbfT);
    // flash attention
    flash_mfma<<<dim3(SEQ / 64, BATCH * NHEADS), 256, 0, stream>>>(qbf, kbf, vbfT, attn);
    // out = attn @ o_w.T
    gemm_bf_mfma<<<dim3(2048 / 128, MROWS / 128), 256, 0, stream>>>(attn, NHEADS * DVDIM, o_w, out, MROWS, 2048, 2048);
}

// Round 5
// 623.365 us; speedup vs baseline: 5.9563x; 1.3173x over previous
//
#include <hip/hip_runtime.h>
#include <hip/hip_bf16.h>
#include <math.h>

// Problem constants (DeepseekV3 MLA prefill)
#define NHEADS 16
#define DQK 192
#define DVDIM 128
#define SEQ 2048
#define BATCH 2
#define MROWS 4096   // BATCH*SEQ
#define HDIM 2048
#define QLORA 1536
#define KVLORA 512
#define SCALING 0.07216878364870323f  // 192^-0.5
#define NTQ 32       // SEQ / 64 q-tiles

typedef __attribute__((ext_vector_type(8))) short short8;
typedef __attribute__((ext_vector_type(4))) float f32x4;

__device__ __forceinline__ float4 ld4(const float* p) {
    return *reinterpret_cast<const float4*>(p);
}

__device__ __forceinline__ unsigned short f2b(float x) {
    __hip_bfloat16 h = __float2bfloat16(x);   // RNE
    return __builtin_bit_cast(unsigned short, h);
}

// =====================================================================
// bf16-MFMA GEMM: C[M,N] (fp32) = A[M,K] (fp32, row stride lda) @ W[N,K]^T
// 128x128 tile, BK=32, 256 threads = 4 waves (2x2), each wave 64x64 out.
// =====================================================================
__global__ __launch_bounds__(256) void gemm_bf_mfma(const float* __restrict__ A, int lda,
                                                    const float* __restrict__ W,
                                                    float* __restrict__ C,
                                                    int M, int N, int K) {
    __shared__ unsigned short As[128 * 32];   // [row][k] row-major, 8KB
    __shared__ unsigned short Bs[128 * 32];   // [ncol][k] row-major, 8KB

    const int tid = threadIdx.x;
    const int bm = blockIdx.y * 128, bn = blockIdx.x * 128;
    const int w = tid >> 6, lane = tid & 63;
    const int wr = (w >> 1) * 64, wc = (w & 1) * 64;
    const int fr = lane & 15, fq = lane >> 4;

    const int srow = tid >> 2;
    const int scol = (tid & 3) * 8;

    f32x4 acc[4][4];
    #pragma unroll
    for (int m = 0; m < 4; m++)
        #pragma unroll
        for (int n = 0; n < 4; n++) acc[m][n] = (f32x4)0.0f;

    const int NT = K >> 5;

    float4 ra[4], rb[4];
    {
        const float* a0 = A + (size_t)(bm + srow) * lda + scol;
        const float* a1 = A + (size_t)(bm + srow + 64) * lda + scol;
        ra[0] = ld4(a0); ra[1] = ld4(a0 + 4);
        ra[2] = ld4(a1); ra[3] = ld4(a1 + 4);
        int g0 = bn + srow;       if (g0 >= N) g0 = N - 1;
        int g1 = bn + srow + 64;  if (g1 >= N) g1 = N - 1;
        const float* b0 = W + (size_t)g0 * K + scol;
        const float* b1 = W + (size_t)g1 * K + scol;
        rb[0] = ld4(b0); rb[1] = ld4(b0 + 4);
        rb[2] = ld4(b1); rb[3] = ld4(b1 + 4);
    }

    for (int t = 0; t < NT; t++) {
        __syncthreads();
        {
            short8 pa0, pa1, pb0, pb1;
            float va[8] = {ra[0].x, ra[0].y, ra[0].z, ra[0].w, ra[1].x, ra[1].y, ra[1].z, ra[1].w};
            float vb[8] = {ra[2].x, ra[2].y, ra[2].z, ra[2].w, ra[3].x, ra[3].y, ra[3].z, ra[3].w};
            float wa[8] = {rb[0].x, rb[0].y, rb[0].z, rb[0].w, rb[1].x, rb[1].y, rb[1].z, rb[1].w};
            float wb[8] = {rb[2].x, rb[2].y, rb[2].z, rb[2].w, rb[3].x, rb[3].y, rb[3].z, rb[3].w};
            #pragma unroll
            for (int j = 0; j < 8; j++) {
                pa0[j] = (short)f2b(va[j]); pa1[j] = (short)f2b(vb[j]);
                pb0[j] = (short)f2b(wa[j]); pb1[j] = (short)f2b(wb[j]);
            }
            *(short8*)&As[srow * 32 + scol]        = pa0;
            *(short8*)&As[(srow + 64) * 32 + scol] = pa1;
            *(short8*)&Bs[srow * 32 + scol]        = pb0;
            *(short8*)&Bs[(srow + 64) * 32 + scol] = pb1;
        }
        __syncthreads();

        if (t + 1 < NT) {
            const int k0 = (t + 1) << 5;
            const float* a0 = A + (size_t)(bm + srow) * lda + k0 + scol;
            const float* a1 = A + (size_t)(bm + srow + 64) * lda + k0 + scol;
            ra[0] = ld4(a0); ra[1] = ld4(a0 + 4);
            ra[2] = ld4(a1); ra[3] = ld4(a1 + 4);
            int g0 = bn + srow;       if (g0 >= N) g0 = N - 1;
            int g1 = bn + srow + 64;  if (g1 >= N) g1 = N - 1;
            const float* b0 = W + (size_t)g0 * K + k0 + scol;
            const float* b1 = W + (size_t)g1 * K + k0 + scol;
            rb[0] = ld4(b0); rb[1] = ld4(b0 + 4);
            rb[2] = ld4(b1); rb[3] = ld4(b1 + 4);
        }

        short8 af[4], bfr[4];
        #pragma unroll
        for (int m = 0; m < 4; m++)
            af[m] = *(const short8*)&As[(wr + m * 16 + fr) * 32 + fq * 8];
        #pragma unroll
        for (int n = 0; n < 4; n++)
            bfr[n] = *(const short8*)&Bs[(wc + n * 16 + fr) * 32 + fq * 8];
        #pragma unroll
        for (int m = 0; m < 4; m++)
            #pragma unroll
            for (int n = 0; n < 4; n++)
                acc[m][n] = __builtin_amdgcn_mfma_f32_16x16x32_bf16(af[m], bfr[n], acc[m][n], 0, 0, 0);
    }

    #pragma unroll
    for (int m = 0; m < 4; m++) {
        #pragma unroll
        for (int n = 0; n < 4; n++) {
            const int col = bn + wc + n * 16 + fr;
            if (col < N) {
                #pragma unroll
                for (int j = 0; j < 4; j++) {
                    const int row = bm + wr + m * 16 + fq * 4 + j;
                    C[(size_t)row * N + col] = acc[m][n][j];
                }
            }
        }
    }
}

// ---------------- RMSNorm in place ----------------
__global__ __launch_bounds__(256) void rmsnorm_ip(float* __restrict__ x,
                                                  const float* __restrict__ w,
                                                  int ncols, int stride) {
    float* xr = x + (size_t)blockIdx.x * stride;
    const int tid = threadIdx.x;
    float ss = 0.f;
    for (int c = tid * 4; c < ncols; c += 1024) {
        float4 v = ld4(xr + c);
        ss += v.x * v.x + v.y * v.y + v.z * v.z + v.w * v.w;
    }
    #pragma unroll
    for (int d = 32; d > 0; d >>= 1) ss += __shfl_down(ss, d);
    __shared__ float wsum[4];
    if ((tid & 63) == 0) wsum[tid >> 6] = ss;
    __syncthreads();
    float total = wsum[0] + wsum[1] + wsum[2] + wsum[3];
    float scale = 1.0f / sqrtf(total / (float)ncols + 1e-6f);
    for (int c = tid * 4; c < ncols; c += 1024) {
        float4 v = ld4(xr + c);
        v.x *= scale * w[c + 0]; v.y *= scale * w[c + 1];
        v.z *= scale * w[c + 2]; v.w *= scale * w[c + 3];
        *(float4*)(xr + c) = v;
    }
}

// ---------------- RoPE cos/sin table (SEQ x 64) ----------
__global__ void rope_table(float* __restrict__ cost, float* __restrict__ sint) {
    int s = blockIdx.x, j = threadIdx.x;
    int i = j & 31;
    float inv = 1.0f / powf(10000.0f, (float)i * (1.0f / 32.0f));
    float ang = (float)s * inv;
    cost[s * 64 + j] = cosf(ang);
    sint[s * 64 + j] = sinf(ang);
}

// ---------------- RoPE k_rope in place (cols 512..575 of kv_a) --------
__global__ __launch_bounds__(256) void rope_k(float* __restrict__ kva,
                                              const float* __restrict__ cost,
                                              const float* __restrict__ sint) {
    int idx = blockIdx.x * 256 + threadIdx.x;
    int row = idx >> 5, j = idx & 31;
    int s = row & (SEQ - 1);
    float* base = kva + (size_t)row * (KVLORA + 64) + KVLORA;
    float x1 = base[j], x2 = base[j + 32];
    float c1 = cost[s * 64 + j],      s1 = sint[s * 64 + j];
    float c2 = cost[s * 64 + j + 32], s2 = sint[s * 64 + j + 32];
    base[j]      = x1 * c1 - x2 * s1;
    base[j + 32] = x2 * c2 + x1 * s2;
}

// ---------------- q convert: fp32 qbuf[4096][3072] -> bf16 qbf[b][h][s][192], rope fused
__global__ __launch_bounds__(256) void rope_q_cvt(const float* __restrict__ qbuf,
                                                  const float* __restrict__ cost,
                                                  const float* __restrict__ sint,
                                                  unsigned short* __restrict__ qbf) {
    const int r = blockIdx.x;            // 0..4095 (b*2048+s)
    const int b = r >> 11, s = r & (SEQ - 1);
    const float* in = qbuf + (size_t)r * 3072;
    for (int i = threadIdx.x; i < 3072; i += 256) {
        const int h = i / DQK, d = i % DQK;
        float val;
        if (d < DVDIM) {
            val = in[h * DQK + d];
        } else {
            const int j = d - DVDIM;
            const float x  = in[h * DQK + DVDIM + j];
            const float rot = (j < 32) ? -in[h * DQK + DVDIM + j + 32]
                                       :  in[h * DQK + DVDIM + j - 32];
            val = x * cost[s * 64 + j] + rot * sint[s * 64 + j];
        }
        qbf[(((size_t)(b * NHEADS + h)) * SEQ + s) * DQK + d] = f2b(val);
    }
}

// ---------------- k convert: kvb k_nope + kva k_rope -> bf16 kbf[b][h][s][192]
__global__ __launch_bounds__(256) void kv_cvt_k(const float* __restrict__ kvb,
                                                const float* __restrict__ kva,
                                                unsigned short* __restrict__ kbf) {
    const int bh = blockIdx.x, st = blockIdx.y;   // bh 0..31, st 0..15 (128 s each)
    const int b = bh >> 4, h = bh & 15;
    const int s0 = st * 128;
    for (int i = threadIdx.x; i < 128 * DQK; i += 256) {
        const int si = i / DQK, d = i % DQK;
        const int r = b * SEQ + s0 + si;
        float val = (d < DVDIM) ? kvb[(size_t)r * 4096 + h * 256 + d]
                                : kva[(size_t)r * (KVLORA + 64) + KVLORA + (d - DVDIM)];
        kbf[(((size_t)bh) * SEQ + s0 + si) * DQK + d] = f2b(val);
    }
}

// ---------------- v convert + transpose: kvb v -> bf16 vbfT[b][h][128][2048]
__global__ __launch_bounds__(256) void kv_cvt_v(const float* __restrict__ kvb,
                                                unsigned short* __restrict__ vbfT) {
    __shared__ unsigned short Vt[64][134];
    const int bh = blockIdx.x, st = blockIdx.y;   // st 0..31 (64 s each)
    const int b = bh >> 4, h = bh & 15;
    const int s0 = st * 64;
    for (int i = threadIdx.x; i < 64 * 128; i += 256) {
        const int si = i >> 7, d = i & 127;
        Vt[si][d] = f2b(kvb[(size_t)(b * SEQ + s0 + si) * 4096 + h * 256 + 128 + d]);
    }
    __syncthreads();
    for (int i = threadIdx.x; i < 128 * 64; i += 256) {
        const int dv = i >> 6, sc = i & 63;
        vbfT[(((size_t)bh) * 128 + dv) * SEQ + s0 + sc] = Vt[sc][dv];
    }
}

// =====================================================================
// bf16-MFMA flash attention v2 (causal, online softmax, fp32 accum)
// - Work-balanced: block bx processes q-tiles bx and 31-bx sequentially
//   (33 KV-tile iterations per block, all 512 blocks equal).
// - K/V staging register double-buffered: next tile's global loads issue
//   right after current tile is written to LDS, hiding HBM latency under
//   QK^T/softmax/PV compute.
// Block: 256 thr = 4 waves, 64 q rows (16/wave). KV tile 64.
// =====================================================================
__global__ __launch_bounds__(256, 2) void flash_mfma(const unsigned short* __restrict__ qbf,
                                                     const unsigned short* __restrict__ kbf,
                                                     const unsigned short* __restrict__ vbfT,
                                                     float* __restrict__ attn) {
    __shared__ unsigned short Ks[64][200];   // [kv][k=192], +8 pad
    __shared__ unsigned short Vs[128][72];   // [dv][kv=64], +8 pad
    __shared__ unsigned short Ps[4][16][72]; // per-wave P [q=16][kv=64], +8 pad

    const int bx = blockIdx.x;               // 0..15 (q-tile pair)
    const int bh = blockIdx.y;
    const int b = bh >> 4, h = bh & 15;
    const int tid = threadIdx.x;
    const int w = tid >> 6, lane = tid & 63;
    const int fr = lane & 15, fq = lane >> 4;

    const unsigned short* Qh = qbf + ((size_t)bh * SEQ) * DQK;
    const unsigned short* Kh = kbf + ((size_t)bh * SEQ) * DQK;
    const unsigned short* Vh = vbfT + ((size_t)bh * 128) * SEQ;

    short8 kreg[6], vreg[4];

    // prefetch KV tile 0
    #pragma unroll
    for (int u = 0; u < 6; u++) {
        int i = tid + u * 256;
        int row = i / 24, c = (i % 24) * 8;
        kreg[u] = *(const short8*)(Kh + (size_t)row * DQK + c);
    }
    #pragma unroll
    for (int u = 0; u < 4; u++) {
        int i = tid + u * 256;
        int row = i >> 3, c = (i & 7) * 8;
        vreg[u] = *(const short8*)(Vh + (size_t)row * SEQ + c);
    }

    #pragma unroll 1
    for (int pass = 0; pass < 2; pass++) {
        const int qt = pass ? (NTQ - 1 - bx) : bx;
        const int q0 = qt * 64;

        // Q fragments for this wave's 16 rows: 6 k-windows of 32
        short8 qf[6];
        {
            const unsigned short* qrow = Qh + (size_t)(q0 + w * 16 + fr) * DQK;
            #pragma unroll
            for (int kw = 0; kw < 6; kw++)
                qf[kw] = *(const short8*)(qrow + kw * 32 + fq * 8);
        }

        f32x4 acc[8];
        #pragma unroll
        for (int n = 0; n < 8; n++) acc[n] = (f32x4)0.0f;
        float mrow[4], lrow[4];
        #pragma unroll
        for (int j = 0; j < 4; j++) { mrow[j] = -3.0e38f; lrow[j] = 0.0f; }

        #pragma unroll 1
        for (int t = 0; t <= qt; t++) {
            __syncthreads();   // previous tile's LDS reads complete
            // write register-staged tile to LDS
            #pragma unroll
            for (int u = 0; u < 6; u++) {
                int i = tid + u * 256;
                int row = i / 24, c = (i % 24) * 8;
                *(short8*)&Ks[row][c] = kreg[u];
            }
            #pragma unroll
            for (int u = 0; u < 4; u++) {
                int i = tid + u * 256;
                int row = i >> 3, c = (i & 7) * 8;
                *(short8*)&Vs[row][c] = vreg[u];
            }
            __syncthreads();

            // issue next tile's global loads (overlap with compute below)
            const int nt = (t < qt) ? (t + 1) : (pass == 0 ? 0 : -1);
            if (nt >= 0) {
                const int kt0n = nt * 64;
                #pragma unroll
                for (int u = 0; u < 6; u++) {
                    int i = tid + u * 256;
                    int row = i / 24, c = (i % 24) * 8;
                    kreg[u] = *(const short8*)(Kh + (size_t)(kt0n + row) * DQK + c);
                }
                #pragma unroll
                for (int u = 0; u < 4; u++) {
                    int i = tid + u * 256;
                    int row = i >> 3, c = (i & 7) * 8;
                    vreg[u] = *(const short8*)(Vh + (size_t)row * SEQ + kt0n + c);
                }
            }

            // S = Q K^T  (wave rows 16 x kv 64)
            f32x4 sfr[4];
            #pragma unroll
            for (int n = 0; n < 4; n++) sfr[n] = (f32x4)0.0f;
            #pragma unroll
            for (int kw = 0; kw < 6; kw++) {
                #pragma unroll
                for (int n = 0; n < 4; n++) {
                    short8 kf = *(const short8*)&Ks[n * 16 + fr][kw * 32 + fq * 8];
                    sfr[n] = __builtin_amdgcn_mfma_f32_16x16x32_bf16(qf[kw], kf, sfr[n], 0, 0, 0);
                }
            }

            // online softmax (per q row = fq*4+j)
            const bool diag = (t == qt);
            float pv[4][4];
            float mnew[4];
            #pragma unroll
            for (int j = 0; j < 4; j++) mnew[j] = mrow[j];
            #pragma unroll
            for (int n = 0; n < 4; n++) {
                #pragma unroll
                for (int j = 0; j < 4; j++) {
                    float s = sfr[n][j] * SCALING;
                    if (diag && (n * 16 + fr > w * 16 + fq * 4 + j)) s = -3.0e38f;
                    pv[n][j] = s;
                    mnew[j] = fmaxf(mnew[j], s);
                }
            }
            #pragma unroll
            for (int j = 0; j < 4; j++) {
                mnew[j] = fmaxf(mnew[j], __shfl_xor(mnew[j], 1));
                mnew[j] = fmaxf(mnew[j], __shfl_xor(mnew[j], 2));
                mnew[j] = fmaxf(mnew[j], __shfl_xor(mnew[j], 4));
                mnew[j] = fmaxf(mnew[j], __shfl_xor(mnew[j], 8));
            }
            float es[4], psum[4];
            #pragma unroll
            for (int j = 0; j < 4; j++) {
                es[j] = __expf(mrow[j] - mnew[j]);
                psum[j] = 0.0f;
            }
            #pragma unroll
            for (int n = 0; n < 4; n++) {
                #pragma unroll
                for (int j = 0; j < 4; j++) {
                    float p = __expf(pv[n][j] - mnew[j]);
                    pv[n][j] = p;
                    psum[j] += p;
                }
            }
            #pragma unroll
            for (int j = 0; j < 4; j++) {
                psum[j] += __shfl_xor(psum[j], 1);
                psum[j] += __shfl_xor(psum[j], 2);
                psum[j] += __shfl_xor(psum[j], 4);
                psum[j] += __shfl_xor(psum[j], 8);
                lrow[j] = lrow[j] * es[j] + psum[j];
                mrow[j] = mnew[j];
            }
            #pragma unroll
            for (int n = 0; n < 8; n++) {
                #pragma unroll
                for (int j = 0; j < 4; j++) acc[n][j] *= es[j];
            }
            // write P (bf16) to wave-private LDS
            #pragma unroll
            for (int n = 0; n < 4; n++) {
                #pragma unroll
                for (int j = 0; j < 4; j++)
                    Ps[w][fq * 4 + j][n * 16 + fr] = f2b(pv[n][j]);
            }
            // PV: O += P V   (A frag from Ps, B frag from Vs = V^T)
            #pragma unroll
            for (int tt = 0; tt < 2; tt++) {
                short8 pa = *(const short8*)&Ps[w][fr][tt * 32 + fq * 8];
                #pragma unroll
                for (int n = 0; n < 8; n++) {
                    short8 vf = *(const short8*)&Vs[n * 16 + fr][tt * 32 + fq * 8];
                    acc[n] = __builtin_amdgcn_mfma_f32_16x16x32_bf16(pa, vf, acc[n], 0, 0, 0);
                }
            }
        }

        // epilogue for this pass
        #pragma unroll
        for (int j = 0; j < 4; j++) {
            const float inv = 1.0f / lrow[j];
            float* orow = attn + (size_t)(b * SEQ + q0 + w * 16 + fq * 4 + j) * (NHEADS * DVDIM) + h * DVDIM;
            #pragma unroll
            for (int n = 0; n < 8; n++)
                orow[n * 16 + fr] = acc[n][j] * inv;
        }
    }
}

extern "C" void kernel_launch(void* const* d_in, const int* in_sizes, int n_in,
                              void* d_out, int out_size, void* d_ws, size_t ws_size,
                              hipStream_t stream) {
    const float* hidden   = (const float*)d_in[0];
    const float* q_a_w    = (const float*)d_in[1];
    const float* q_a_ln_w = (const float*)d_in[2];
    const float* q_b_w    = (const float*)d_in[3];
    const float* kv_a_w   = (const float*)d_in[4];
    const float* kv_a_ln_w= (const float*)d_in[5];
    const float* kv_b_w   = (const float*)d_in[6];
    const float* o_w      = (const float*)d_in[7];
    float* out = (float*)d_out;

    float* ws = (float*)d_ws;
    const size_t off_qa   = 0;                               // 4096*1536 f32
    const size_t off_q    = off_qa   + (size_t)4096 * 1536;  // 4096*3072 f32
    const size_t off_kva  = off_q    + (size_t)4096 * 3072;  // 4096*576  f32
    const size_t off_kv   = off_kva  + (size_t)4096 * 576;   // 4096*4096 f32
    const size_t off_attn = off_kv   + (size_t)4096 * 4096;  // 4096*2048 f32
    const size_t off_cos  = off_attn + (size_t)4096 * 2048;
    const size_t off_sin  = off_cos  + (size_t)2048 * 64;
    float* qa   = ws + off_qa;
    float* qbuf = ws + off_q;
    float* kva  = ws + off_kva;
    float* kvb  = ws + off_kv;
    float* attn = ws + off_attn;
    float* cosb = ws + off_cos;
    float* sinb = ws + off_sin;

    // bf16 overlays on dead fp32 buffers:
    unsigned short* qbf  = (unsigned short*)qa;    // 25.2MB <= qa (25.2MB)
    unsigned short* kbf  = (unsigned short*)qbuf;  // 25.2MB
    unsigned short* vbfT = (unsigned short*)qbuf + (size_t)2 * 16 * 2048 * 192;  // +16.8MB <= qbuf (50.3MB)

    // q_a = hidden @ q_a_w.T
    gemm_bf_mfma<<<dim3(1536 / 128, MROWS / 128), 256, 0, stream>>>(hidden, HDIM, q_a_w, qa, MROWS, 1536, 2048);
    // kv_a = hidden @ kv_a_w.T
    gemm_bf_mfma<<<dim3((576 + 127) / 128, MROWS / 128), 256, 0, stream>>>(hidden, HDIM, kv_a_w, kva, MROWS, 576, 2048);
    rmsnorm_ip<<<MROWS, 256, 0, stream>>>(qa, q_a_ln_w, QLORA, QLORA);
    rmsnorm_ip<<<MROWS, 256, 0, stream>>>(kva, kv_a_ln_w, KVLORA, KVLORA + 64);
    rope_table<<<SEQ, 64, 0, stream>>>(cosb, sinb);
    // q = norm(q_a) @ q_b_w.T
    gemm_bf_mfma<<<dim3(3072 / 128, MROWS / 128), 256, 0, stream>>>(qa, QLORA, q_b_w, qbuf, MROWS, 3072, 1536);
    // kv = norm(c_kv) @ kv_b_w.T
    gemm_bf_mfma<<<dim3(4096 / 128, MROWS / 128), 256, 0, stream>>>(kva, KVLORA + 64, kv_b_w, kvb, MROWS, 4096, 512);
    // rope k in place, then converters
    rope_k<<<(MROWS * 32) / 256, 256, 0, stream>>>(kva, cosb, sinb);
    rope_q_cvt<<<MROWS, 256, 0, stream>>>(qbuf, cosb, sinb, qbf);
    kv_cvt_k<<<dim3(32, 16), 256, 0, stream>>>(kvb, kva, kbf);
    kv_cvt_v<<<dim3(32, 32), 256, 0, stream>>>(kvb, vbfT);
    // flash attention (work-paired causal blocks)
    flash_mfma<<<dim3(NTQ / 2, BATCH * NHEADS), 256, 0, stream>>>(qbf, kbf, vbfT, attn);
    // out = attn @ o_w.T
    gemm_bf_mfma<<<dim3(2048 / 128, MROWS / 128), 256, 0, stream>>>(attn, NHEADS * DVDIM, o_w, out, MROWS, 2048, 2048);
}

// Round 6
// 588.120 us; speedup vs baseline: 6.3132x; 1.0599x over previous
//
#include <hip/hip_runtime.h>
#include <hip/hip_bf16.h>
#include <math.h>
#include <stdint.h>

// Problem constants (DeepseekV3 MLA prefill)
#define NHEADS 16
#define DQK 192
#define DVDIM 128
#define SEQ 2048
#define BATCH 2
#define MROWS 4096   // BATCH*SEQ
#define HDIM 2048
#define QLORA 1536
#define KVLORA 512
#define SCALING 0.07216878364870323f  // 192^-0.5
#define NTQ 32       // SEQ / 64 q-tiles

typedef __attribute__((ext_vector_type(8))) short short8;
typedef __attribute__((ext_vector_type(4))) short short4v;
typedef __attribute__((ext_vector_type(4))) float f32x4;

__device__ __forceinline__ float4 ld4(const float* p) {
    return *reinterpret_cast<const float4*>(p);
}
__device__ __forceinline__ unsigned short f2b(float x) {
    __hip_bfloat16 h = __float2bfloat16(x);   // RNE
    return __builtin_bit_cast(unsigned short, h);
}
// async global->LDS, 16B per lane; LDS dest = wave-uniform base + lane*16 (HW rule).
__device__ __forceinline__ void gload16(const void* g, void* l) {
    typedef const __attribute__((address_space(1))) unsigned int ga_t;
    typedef __attribute__((address_space(3))) unsigned int ls_t;
    __builtin_amdgcn_global_load_lds((ga_t*)(uintptr_t)g, (ls_t*)(uintptr_t)l, 16, 0, 0);
}

// ---------------- flat fp32 -> bf16 convert (8 elems/thread) ----------------
__global__ __launch_bounds__(256) void cvt_bf(const float* __restrict__ in,
                                              unsigned short* __restrict__ o, int n8) {
    int i = blockIdx.x * 256 + threadIdx.x;
    if (i >= n8) return;
    float4 a = ld4(in + (size_t)i * 8), b = ld4(in + (size_t)i * 8 + 4);
    short8 t;
    t[0] = (short)f2b(a.x); t[1] = (short)f2b(a.y); t[2] = (short)f2b(a.z); t[3] = (short)f2b(a.w);
    t[4] = (short)f2b(b.x); t[5] = (short)f2b(b.y); t[6] = (short)f2b(b.z); t[7] = (short)f2b(b.w);
    *(short8*)(o + (size_t)i * 8) = t;
}

// =====================================================================
// Pure-bf16 MFMA GEMM with global_load_lds staging (m97 structure):
// C = A[M,K](bf16, stride lda) @ W[N,K]^T(bf16).  128x128 tile, BK=32,
// 256 thr = 4 waves (2x2 of 64x64). Templated epilogue:
//   EPI 0: fp32 C[row*ldc + col] (guard col<N)
//   EPI 1: q_b -> qbf bf16 [b*16+h][s][192] with RoPE fused (pairs via acc[n^2])
//   EPI 2: kv_b -> kbf bf16 [bh][s][192] (d<128) + vbfT bf16 [bh][dv][2048]
// =====================================================================
template <int EPI>
__global__ __launch_bounds__(256) void gemm_bf16(const unsigned short* __restrict__ A, int lda,
                                                 const unsigned short* __restrict__ W, int wrows,
                                                 float* __restrict__ Cf, int ldc, int N,
                                                 unsigned short* __restrict__ O1,
                                                 unsigned short* __restrict__ O2,
                                                 const float* __restrict__ cosb,
                                                 const float* __restrict__ sinb,
                                                 int K) {
    __shared__ unsigned short As[128 * 32];   // [row][k] row-major, 8KB
    __shared__ unsigned short Bs[128 * 32];

    const int tid = threadIdx.x;
    const int bm = blockIdx.y * 128, bn = blockIdx.x * 128;
    const int w = tid >> 6, lane = tid & 63;
    const int wr = (w >> 1) * 64, wc = (w & 1) * 64;
    const int fr = lane & 15, fq = lane >> 4;

    // staging: wave w owns rows w*32..w*32+31 of each tile; 2 load_lds per operand.
    // lane l -> row r0 = w*32 + l/4, col c0 = (l&3)*8; LDS chunk base + l*16B matches.
    const int r0 = w * 32 + (lane >> 2);
    const int c0 = (lane & 3) * 8;
    const unsigned short* Ag0 = A + (size_t)(bm + r0) * lda + c0;
    const unsigned short* Ag1 = Ag0 + (size_t)16 * lda;
    int br0 = bn + r0;      if (br0 >= wrows) br0 = wrows - 1;
    int br1 = bn + r0 + 16; if (br1 >= wrows) br1 = wrows - 1;
    const unsigned short* Wg0 = W + (size_t)br0 * K + c0;
    const unsigned short* Wg1 = W + (size_t)br1 * K + c0;
    unsigned short* Al0 = &As[(w * 32) * 32];
    unsigned short* Al1 = &As[(w * 32 + 16) * 32];
    unsigned short* Bl0 = &Bs[(w * 32) * 32];
    unsigned short* Bl1 = &Bs[(w * 32 + 16) * 32];

    f32x4 acc[4][4];
    #pragma unroll
    for (int m = 0; m < 4; m++)
        #pragma unroll
        for (int n = 0; n < 4; n++) acc[m][n] = (f32x4)0.0f;

    for (int t = 0; t < K; t += 32) {
        __syncthreads();             // prior compute done reading LDS
        gload16(Ag0 + t, Al0);
        gload16(Ag1 + t, Al1);
        gload16(Wg0 + t, Bl0);
        gload16(Wg1 + t, Bl1);
        __syncthreads();             // compiler drains vmcnt(0) -> tile resident

        short8 af[4], bfr[4];
        #pragma unroll
        for (int m = 0; m < 4; m++)
            af[m] = *(const short8*)&As[(wr + m * 16 + fr) * 32 + fq * 8];
        #pragma unroll
        for (int n = 0; n < 4; n++)
            bfr[n] = *(const short8*)&Bs[(wc + n * 16 + fr) * 32 + fq * 8];
        #pragma unroll
        for (int m = 0; m < 4; m++)
            #pragma unroll
            for (int n = 0; n < 4; n++)
                acc[m][n] = __builtin_amdgcn_mfma_f32_16x16x32_bf16(af[m], bfr[n], acc[m][n], 0, 0, 0);
    }

    // C/D layout: col = wc + n*16 + fr, row = wr + m*16 + fq*4 + j   [m89-verified]
    if constexpr (EPI == 0) {
        #pragma unroll
        for (int m = 0; m < 4; m++) {
            #pragma unroll
            for (int n = 0; n < 4; n++) {
                const int col = bn + wc + n * 16 + fr;
                if (col < N) {
                    #pragma unroll
                    for (int j = 0; j < 4; j++)
                        Cf[(size_t)(bm + wr + m * 16 + fq * 4 + j) * ldc + col] = acc[m][n][j];
                }
            }
        }
    } else if constexpr (EPI == 1) {
        #pragma unroll
        for (int n = 0; n < 4; n++) {
            const int col = bn + wc + n * 16 + fr;    // 0..3071
            const int h = col / DQK, d = col % DQK;
            #pragma unroll
            for (int m = 0; m < 4; m++) {
                #pragma unroll
                for (int j = 0; j < 4; j++) {
                    const int row = bm + wr + m * 16 + fq * 4 + j;
                    const int s = row & (SEQ - 1), b = row >> 11;
                    float v = acc[m][n][j];
                    if (d >= DVDIM) {
                        const int j5 = d - DVDIM;                 // 0..63
                        const float partner = acc[m][n ^ 2][j];   // col ^ 32 (same head)
                        const float rot = (j5 < 32) ? -partner : partner;
                        v = v * cosb[s * 64 + j5] + rot * sinb[s * 64 + j5];
                    }
                    O1[((size_t)(b * NHEADS + h) * SEQ + s) * DQK + d] = f2b(v);
                }
            }
        }
    } else {
        #pragma unroll
        for (int n = 0; n < 4; n++) {
            const int col = bn + wc + n * 16 + fr;    // 0..4095
            const int h = col >> 8, d = col & 255;
            #pragma unroll
            for (int m = 0; m < 4; m++) {
                #pragma unroll
                for (int j = 0; j < 4; j++) {
                    const int row = bm + wr + m * 16 + fq * 4 + j;
                    const int s = row & (SEQ - 1);
                    const int bh = (row >> 11) * NHEADS + h;
                    const unsigned short v = f2b(acc[m][n][j]);
                    if (d < DVDIM) O1[((size_t)bh * SEQ + s) * DQK + d] = v;          // k_nope
                    else           O2[((size_t)bh * DVDIM + (d - DVDIM)) * SEQ + s] = v; // V^T
                }
            }
        }
    }
}

// ---------------- RMSNorm: fp32 in (row stride instride) -> bf16 out (tight) ----
__global__ __launch_bounds__(256) void rmsnorm_bf(const float* __restrict__ x,
                                                  const float* __restrict__ w,
                                                  unsigned short* __restrict__ o,
                                                  int ncols, int instride) {
    const float* xr = x + (size_t)blockIdx.x * instride;
    unsigned short* orow = o + (size_t)blockIdx.x * ncols;
    const int tid = threadIdx.x;
    float ss = 0.f;
    for (int c = tid * 4; c < ncols; c += 1024) {
        float4 v = ld4(xr + c);
        ss += v.x * v.x + v.y * v.y + v.z * v.z + v.w * v.w;
    }
    #pragma unroll
    for (int d = 32; d > 0; d >>= 1) ss += __shfl_down(ss, d);
    __shared__ float wsum[4];
    if ((tid & 63) == 0) wsum[tid >> 6] = ss;
    __syncthreads();
    float total = wsum[0] + wsum[1] + wsum[2] + wsum[3];
    float scale = 1.0f / sqrtf(total / (float)ncols + 1e-6f);
    for (int c = tid * 4; c < ncols; c += 1024) {
        float4 v = ld4(xr + c);
        short4v t;
        t[0] = (short)f2b(v.x * scale * w[c + 0]);
        t[1] = (short)f2b(v.y * scale * w[c + 1]);
        t[2] = (short)f2b(v.z * scale * w[c + 2]);
        t[3] = (short)f2b(v.w * scale * w[c + 3]);
        *(short4v*)&orow[c] = t;
    }
}

// ---------------- RoPE cos/sin table (SEQ x 64) ----------
__global__ void rope_table(float* __restrict__ cost, float* __restrict__ sint) {
    int s = blockIdx.x, j = threadIdx.x;
    int i = j & 31;
    float inv = 1.0f / powf(10000.0f, (float)i * (1.0f / 32.0f));
    float ang = (float)s * inv;
    cost[s * 64 + j] = cosf(ang);
    sint[s * 64 + j] = sinf(ang);
}

// ---------------- k_rope: rope(kva cols 512..575) -> kbf[..][128..191], bcast 16 heads
__global__ void rope_k_bcast(const float* __restrict__ kva,
                             const float* __restrict__ cost,
                             const float* __restrict__ sint,
                             unsigned short* __restrict__ kbf) {
    const int r = blockIdx.x;        // 0..4095
    const int j = threadIdx.x;       // 0..63
    const int b = r >> 11, s = r & (SEQ - 1);
    const float* base = kva + (size_t)r * (KVLORA + 64) + KVLORA;
    const float x = base[j];
    const float rot = (j < 32) ? -base[j + 32] : base[j - 32];
    const unsigned short v = f2b(x * cost[s * 64 + j] + rot * sint[s * 64 + j]);
    #pragma unroll
    for (int h = 0; h < NHEADS; h++)
        kbf[((size_t)(b * NHEADS + h) * SEQ + s) * DQK + DVDIM + j] = v;
}

// =====================================================================
// bf16-MFMA flash attention (causal, online softmax, fp32 accum, bf16 out)
// Work-balanced pairs + register double-buffered K/V staging (round-5 proven).
// =====================================================================
__global__ __launch_bounds__(256, 2) void flash_mfma(const unsigned short* __restrict__ qbf,
                                                     const unsigned short* __restrict__ kbf,
                                                     const unsigned short* __restrict__ vbfT,
                                                     unsigned short* __restrict__ attn) {
    __shared__ unsigned short Ks[64][200];
    __shared__ unsigned short Vs[128][72];
    __shared__ unsigned short Ps[4][16][72];

    const int bx = blockIdx.x;
    const int bh = blockIdx.y;
    const int b = bh >> 4, h = bh & 15;
    const int tid = threadIdx.x;
    const int w = tid >> 6, lane = tid & 63;
    const int fr = lane & 15, fq = lane >> 4;

    const unsigned short* Qh = qbf + ((size_t)bh * SEQ) * DQK;
    const unsigned short* Kh = kbf + ((size_t)bh * SEQ) * DQK;
    const unsigned short* Vh = vbfT + ((size_t)bh * 128) * SEQ;

    short8 kreg[6], vreg[4];
    #pragma unroll
    for (int u = 0; u < 6; u++) {
        int i = tid + u * 256;
        int row = i / 24, c = (i % 24) * 8;
        kreg[u] = *(const short8*)(Kh + (size_t)row * DQK + c);
    }
    #pragma unroll
    for (int u = 0; u < 4; u++) {
        int i = tid + u * 256;
        int row = i >> 3, c = (i & 7) * 8;
        vreg[u] = *(const short8*)(Vh + (size_t)row * SEQ + c);
    }

    #pragma unroll 1
    for (int pass = 0; pass < 2; pass++) {
        const int qt = pass ? (NTQ - 1 - bx) : bx;
        const int q0 = qt * 64;

        short8 qf[6];
        {
            const unsigned short* qrow = Qh + (size_t)(q0 + w * 16 + fr) * DQK;
            #pragma unroll
            for (int kw = 0; kw < 6; kw++)
                qf[kw] = *(const short8*)(qrow + kw * 32 + fq * 8);
        }

        f32x4 acc[8];
        #pragma unroll
        for (int n = 0; n < 8; n++) acc[n] = (f32x4)0.0f;
        float mrow[4], lrow[4];
        #pragma unroll
        for (int j = 0; j < 4; j++) { mrow[j] = -3.0e38f; lrow[j] = 0.0f; }

        #pragma unroll 1
        for (int t = 0; t <= qt; t++) {
            __syncthreads();
            #pragma unroll
            for (int u = 0; u < 6; u++) {
                int i = tid + u * 256;
                int row = i / 24, c = (i % 24) * 8;
                *(short8*)&Ks[row][c] = kreg[u];
            }
            #pragma unroll
            for (int u = 0; u < 4; u++) {
                int i = tid + u * 256;
                int row = i >> 3, c = (i & 7) * 8;
                *(short8*)&Vs[row][c] = vreg[u];
            }
            __syncthreads();

            const int nt = (t < qt) ? (t + 1) : (pass == 0 ? 0 : -1);
            if (nt >= 0) {
                const int kt0n = nt * 64;
                #pragma unroll
                for (int u = 0; u < 6; u++) {
                    int i = tid + u * 256;
                    int row = i / 24, c = (i % 24) * 8;
                    kreg[u] = *(const short8*)(Kh + (size_t)(kt0n + row) * DQK + c);
                }
                #pragma unroll
                for (int u = 0; u < 4; u++) {
                    int i = tid + u * 256;
                    int row = i >> 3, c = (i & 7) * 8;
                    vreg[u] = *(const short8*)(Vh + (size_t)row * SEQ + kt0n + c);
                }
            }

            f32x4 sfr[4];
            #pragma unroll
            for (int n = 0; n < 4; n++) sfr[n] = (f32x4)0.0f;
            #pragma unroll
            for (int kw = 0; kw < 6; kw++) {
                #pragma unroll
                for (int n = 0; n < 4; n++) {
                    short8 kf = *(const short8*)&Ks[n * 16 + fr][kw * 32 + fq * 8];
                    sfr[n] = __builtin_amdgcn_mfma_f32_16x16x32_bf16(qf[kw], kf, sfr[n], 0, 0, 0);
                }
            }

            const bool diag = (t == qt);
            float pv[4][4];
            float mnew[4];
            #pragma unroll
            for (int j = 0; j < 4; j++) mnew[j] = mrow[j];
            #pragma unroll
            for (int n = 0; n < 4; n++) {
                #pragma unroll
                for (int j = 0; j < 4; j++) {
                    float s = sfr[n][j] * SCALING;
                    if (diag && (n * 16 + fr > w * 16 + fq * 4 + j)) s = -3.0e38f;
                    pv[n][j] = s;
                    mnew[j] = fmaxf(mnew[j], s);
                }
            }
            #pragma unroll
            for (int j = 0; j < 4; j++) {
                mnew[j] = fmaxf(mnew[j], __shfl_xor(mnew[j], 1));
                mnew[j] = fmaxf(mnew[j], __shfl_xor(mnew[j], 2));
                mnew[j] = fmaxf(mnew[j], __shfl_xor(mnew[j], 4));
                mnew[j] = fmaxf(mnew[j], __shfl_xor(mnew[j], 8));
            }
            float es[4], psum[4];
            #pragma unroll
            for (int j = 0; j < 4; j++) {
                es[j] = __expf(mrow[j] - mnew[j]);
                psum[j] = 0.0f;
            }
            #pragma unroll
            for (int n = 0; n < 4; n++) {
                #pragma unroll
                for (int j = 0; j < 4; j++) {
                    float p = __expf(pv[n][j] - mnew[j]);
                    pv[n][j] = p;
                    psum[j] += p;
                }
            }
            #pragma unroll
            for (int j = 0; j < 4; j++) {
                psum[j] += __shfl_xor(psum[j], 1);
                psum[j] += __shfl_xor(psum[j], 2);
                psum[j] += __shfl_xor(psum[j], 4);
                psum[j] += __shfl_xor(psum[j], 8);
                lrow[j] = lrow[j] * es[j] + psum[j];
                mrow[j] = mnew[j];
            }
            #pragma unroll
            for (int n = 0; n < 8; n++) {
                #pragma unroll
                for (int j = 0; j < 4; j++) acc[n][j] *= es[j];
            }
            #pragma unroll
            for (int n = 0; n < 4; n++) {
                #pragma unroll
                for (int j = 0; j < 4; j++)
                    Ps[w][fq * 4 + j][n * 16 + fr] = f2b(pv[n][j]);
            }
            #pragma unroll
            for (int tt = 0; tt < 2; tt++) {
                short8 pa = *(const short8*)&Ps[w][fr][tt * 32 + fq * 8];
                #pragma unroll
                for (int n = 0; n < 8; n++) {
                    short8 vf = *(const short8*)&Vs[n * 16 + fr][tt * 32 + fq * 8];
                    acc[n] = __builtin_amdgcn_mfma_f32_16x16x32_bf16(pa, vf, acc[n], 0, 0, 0);
                }
            }
        }

        // epilogue: bf16 attn [row][h*128 + dv]
        #pragma unroll
        for (int j = 0; j < 4; j++) {
            const float inv = 1.0f / lrow[j];
            unsigned short* orow = attn + (size_t)(b * SEQ + q0 + w * 16 + fq * 4 + j) * (NHEADS * DVDIM) + h * DVDIM;
            #pragma unroll
            for (int n = 0; n < 8; n++)
                orow[n * 16 + fr] = f2b(acc[n][j] * inv);
        }
    }
}

extern "C" void kernel_launch(void* const* d_in, const int* in_sizes, int n_in,
                              void* d_out, int out_size, void* d_ws, size_t ws_size,
                              hipStream_t stream) {
    const float* hidden   = (const float*)d_in[0];
    const float* q_a_w    = (const float*)d_in[1];
    const float* q_a_ln_w = (const float*)d_in[2];
    const float* q_b_w    = (const float*)d_in[3];
    const float* kv_a_w   = (const float*)d_in[4];
    const float* kv_a_ln_w= (const float*)d_in[5];
    const float* kv_b_w   = (const float*)d_in[6];
    const float* o_w      = (const float*)d_in[7];
    float* out = (float*)d_out;

    char* base = (char*)d_ws;
    size_t off = 0;
    auto alloc = [&](size_t bytes) -> void* {
        void* p = base + off;
        off += (bytes + 255) & ~(size_t)255;
        return p;
    };
    float* qa            = (float*)alloc((size_t)MROWS * QLORA * 4);          // 25.2MB
    float* kva           = (float*)alloc((size_t)MROWS * (KVLORA + 64) * 4);  // 9.4MB
    float* cosb          = (float*)alloc((size_t)SEQ * 64 * 4);
    float* sinb          = (float*)alloc((size_t)SEQ * 64 * 4);
    unsigned short* hbf  = (unsigned short*)alloc((size_t)MROWS * HDIM * 2);       // 16.8MB
    unsigned short* w_qa = (unsigned short*)alloc((size_t)QLORA * HDIM * 2);       // 6.3MB
    unsigned short* w_qb = (unsigned short*)alloc((size_t)3072 * QLORA * 2);       // 9.4MB
    unsigned short* w_kva= (unsigned short*)alloc((size_t)576 * HDIM * 2);         // 2.4MB
    unsigned short* w_kvb= (unsigned short*)alloc((size_t)4096 * KVLORA * 2);      // 4.2MB
    unsigned short* w_o  = (unsigned short*)alloc((size_t)HDIM * 2048 * 2);        // 8.4MB
    unsigned short* qabf = (unsigned short*)alloc((size_t)MROWS * QLORA * 2);      // 12.6MB
    unsigned short* ckvbf= (unsigned short*)alloc((size_t)MROWS * KVLORA * 2);     // 4.2MB
    unsigned short* qbf  = (unsigned short*)alloc((size_t)32 * SEQ * DQK * 2);     // 25.2MB
    unsigned short* kbf  = (unsigned short*)alloc((size_t)32 * SEQ * DQK * 2);     // 25.2MB
    unsigned short* vbfT = (unsigned short*)alloc((size_t)32 * DVDIM * SEQ * 2);   // 16.8MB
    unsigned short* attnbf=(unsigned short*)alloc((size_t)MROWS * 2048 * 2);       // 16.8MB
    // total ~183.8MB (fits known-good 186.6MB footprint)

    // bf16 conversions (every launch; ws re-poisoned by harness)
    cvt_bf<<<4096, 256, 0, stream>>>(hidden, hbf, 1048576);
    cvt_bf<<<1536, 256, 0, stream>>>(q_a_w,  w_qa, 393216);
    cvt_bf<<<2304, 256, 0, stream>>>(q_b_w,  w_qb, 589824);
    cvt_bf<<< 576, 256, 0, stream>>>(kv_a_w, w_kva, 147456);
    cvt_bf<<<1024, 256, 0, stream>>>(kv_b_w, w_kvb, 262144);
    cvt_bf<<<2048, 256, 0, stream>>>(o_w,    w_o,  524288);
    rope_table<<<SEQ, 64, 0, stream>>>(cosb, sinb);

    // q_a = hidden @ q_a_w.T -> fp32 qa
    gemm_bf16<0><<<dim3(12, 32), 256, 0, stream>>>(hbf, HDIM, w_qa, QLORA, qa, QLORA, QLORA,
                                                   nullptr, nullptr, nullptr, nullptr, HDIM);
    // kv_a = hidden @ kv_a_w.T -> fp32 kva (stride 576)
    gemm_bf16<0><<<dim3(5, 32), 256, 0, stream>>>(hbf, HDIM, w_kva, 576, kva, 576, 576,
                                                  nullptr, nullptr, nullptr, nullptr, HDIM);
    // rmsnorms -> bf16 activations
    rmsnorm_bf<<<MROWS, 256, 0, stream>>>(qa, q_a_ln_w, qabf, QLORA, QLORA);
    rmsnorm_bf<<<MROWS, 256, 0, stream>>>(kva, kv_a_ln_w, ckvbf, KVLORA, KVLORA + 64);
    // q = norm(q_a) @ q_b_w.T -> qbf (RoPE fused in epilogue)
    gemm_bf16<1><<<dim3(24, 32), 256, 0, stream>>>(qabf, QLORA, w_qb, 3072, nullptr, 0, 3072,
                                                   qbf, nullptr, cosb, sinb, QLORA);
    // kv = norm(c_kv) @ kv_b_w.T -> kbf (k_nope) + vbfT (V transposed)
    gemm_bf16<2><<<dim3(32, 32), 256, 0, stream>>>(ckvbf, KVLORA, w_kvb, 4096, nullptr, 0, 4096,
                                                   kbf, vbfT, nullptr, nullptr, KVLORA);
    // roped k_rope broadcast into kbf cols 128..191
    rope_k_bcast<<<MROWS, 64, 0, stream>>>(kva, cosb, sinb, kbf);
    // flash attention -> bf16 attn
    flash_mfma<<<dim3(NTQ / 2, BATCH * NHEADS), 256, 0, stream>>>(qbf, kbf, vbfT, attnbf);
    // out = attn @ o_w.T -> fp32 d_out
    gemm_bf16<0><<<dim3(16, 32), 256, 0, stream>>>(attnbf, 2048, w_o, HDIM, out, HDIM, HDIM,
                                                   nullptr, nullptr, nullptr, nullptr, 2048);
}

// Round 7
// 502.880 us; speedup vs baseline: 7.3834x; 1.1695x over previous
//
#include <hip/hip_runtime.h>
#include <hip/hip_bf16.h>
#include <math.h>
#include <stdint.h>

// Problem constants (DeepseekV3 MLA prefill)
#define NHEADS 16
#define DQK 192
#define DVDIM 128
#define SEQ 2048
#define BATCH 2
#define MROWS 4096   // BATCH*SEQ
#define HDIM 2048
#define QLORA 1536
#define KVLORA 512
#define SCALING 0.07216878364870323f  // 192^-0.5
#define NTQ 32       // SEQ / 64 q-tiles

typedef __attribute__((ext_vector_type(8))) short short8;
typedef __attribute__((ext_vector_type(4))) short short4v;
typedef __attribute__((ext_vector_type(4))) float f32x4;

__device__ __forceinline__ float4 ld4(const float* p) {
    return *reinterpret_cast<const float4*>(p);
}
__device__ __forceinline__ unsigned short f2b(float x) {
    __hip_bfloat16 h = __float2bfloat16(x);   // RNE
    return __builtin_bit_cast(unsigned short, h);
}
// async global->LDS, 16B per lane; LDS dest = wave-uniform base, HW adds lane*16.
__device__ __forceinline__ void gload16(const void* g, void* l) {
    typedef const __attribute__((address_space(1))) unsigned int ga_t;
    typedef __attribute__((address_space(3))) unsigned int ls_t;
    __builtin_amdgcn_global_load_lds((ga_t*)(uintptr_t)g, (ls_t*)(uintptr_t)l, 16, 0, 0);
}

// ---------------- flat fp32 -> bf16 convert (8 elems/thread) ----------------
__global__ __launch_bounds__(256) void cvt_bf(const float* __restrict__ in,
                                              unsigned short* __restrict__ o, int n8) {
    int i = blockIdx.x * 256 + threadIdx.x;
    if (i >= n8) return;
    float4 a = ld4(in + (size_t)i * 8), b = ld4(in + (size_t)i * 8 + 4);
    short8 t;
    t[0] = (short)f2b(a.x); t[1] = (short)f2b(a.y); t[2] = (short)f2b(a.z); t[3] = (short)f2b(a.w);
    t[4] = (short)f2b(b.x); t[5] = (short)f2b(b.y); t[6] = (short)f2b(b.z); t[7] = (short)f2b(b.w);
    *(short8*)(o + (size_t)i * 8) = t;
}

// =====================================================================
// Pure-bf16 MFMA GEMM, 128x128 tile, BK=32, 4 waves, 2-phase LDS
// double-buffer (T3-minimum): STAGE(next) -> read cur -> MFMA -> barrier.
// C = A[M,K] @ W[N,K]^T.  MODE:
//  0: fp32 C[row*ldc+col]                       (attn @ o_w)
//  1: fused q_a|kv_a: W rows<1536 from W, else W2 (clamp 576); fp32 out
//     ldc=2112, guard col<2112
//  2: q_b -> qbf bf16 [bh][s][192], RoPE fused via acc[n^2]
//  3: kv_b k_nope -> kbf[bh][s][192] (W row remap h*256+d)
//  4: V^T: A = kv_b weights (row remap h*256+128+dv), W-side = ckv acts;
//     out vbfT[bh][dv][s]
// =====================================================================
template <int MODE>
__global__ __launch_bounds__(256) void gemm_bf16(
        const unsigned short* __restrict__ A, int lda,
        const unsigned short* __restrict__ W, const unsigned short* __restrict__ W2,
        float* __restrict__ Cf, int ldc,
        unsigned short* __restrict__ O1, unsigned short* __restrict__ O2,
        const float* __restrict__ cosb, const float* __restrict__ sinb,
        int K) {
    __shared__ unsigned short As[2][128 * 32];
    __shared__ unsigned short Bs[2][128 * 32];

    const int tid = threadIdx.x;
    const int bm = blockIdx.y * 128, bn = blockIdx.x * 128;
    const int w = tid >> 6, lane = tid & 63;
    const int wr = (w >> 1) * 64, wc = (w & 1) * 64;
    const int fr = lane & 15, fq = lane >> 4;

    // staging coords: wave w stages rows w*32..+31 (two 16-row chunks)
    const int r0 = w * 32 + (lane >> 2);
    const int c0 = (lane & 3) * 8;

    const unsigned short* Ag0;
    if constexpr (MODE == 4) {
        Ag0 = A + (size_t)((bm >> 7) * 256 + 128 + r0) * lda + c0;   // v-feature remap
    } else {
        Ag0 = A + (size_t)(bm + r0) * lda + c0;
    }
    const unsigned short* Ag1 = Ag0 + (size_t)16 * lda;

    const unsigned short* Wg0;
    const unsigned short* Wg1;
    if constexpr (MODE == 1) {
        if (bn < 1536) {
            Wg0 = W + (size_t)(bn + r0) * K + c0;
            Wg1 = Wg0 + (size_t)16 * K;
        } else {
            int br0 = bn - 1536 + r0;      if (br0 > 575) br0 = 575;
            int br1 = bn - 1536 + r0 + 16; if (br1 > 575) br1 = 575;
            Wg0 = W2 + (size_t)br0 * K + c0;
            Wg1 = W2 + (size_t)br1 * K + c0;
        }
    } else if constexpr (MODE == 3) {
        Wg0 = W + (size_t)((bn >> 7) * 256 + r0) * K + c0;           // k_nope remap
        Wg1 = Wg0 + (size_t)16 * K;
    } else {
        Wg0 = W + (size_t)(bn + r0) * K + c0;
        Wg1 = Wg0 + (size_t)16 * K;
    }

#define STAGE(buf, koff) do { \
        gload16(Ag0 + (koff), &As[buf][(w * 32) * 32]); \
        gload16(Ag1 + (koff), &As[buf][(w * 32 + 16) * 32]); \
        gload16(Wg0 + (koff), &Bs[buf][(w * 32) * 32]); \
        gload16(Wg1 + (koff), &Bs[buf][(w * 32 + 16) * 32]); \
    } while (0)

    f32x4 acc[4][4];
    #pragma unroll
    for (int m = 0; m < 4; m++)
        #pragma unroll
        for (int n = 0; n < 4; n++) acc[m][n] = (f32x4)0.0f;

    const int NT = K >> 5;
    STAGE(0, 0);
    __syncthreads();               // drain vmcnt(0); tile 0 resident
    int cur = 0;
    for (int t = 0; t < NT; t++) {
        const int kn = (t + 1 < NT) ? (t + 1) * 32 : 0;
        STAGE(cur ^ 1, kn);        // in flight across the MFMA phase

        short8 af[4], bfr[4];
        #pragma unroll
        for (int m = 0; m < 4; m++)
            af[m] = *(const short8*)&As[cur][(wr + m * 16 + fr) * 32 + fq * 8];
        #pragma unroll
        for (int n = 0; n < 4; n++)
            bfr[n] = *(const short8*)&Bs[cur][(wc + n * 16 + fr) * 32 + fq * 8];
        #pragma unroll
        for (int m = 0; m < 4; m++)
            #pragma unroll
            for (int n = 0; n < 4; n++)
                acc[m][n] = __builtin_amdgcn_mfma_f32_16x16x32_bf16(af[m], bfr[n], acc[m][n], 0, 0, 0);

        __syncthreads();           // drains vmcnt(0): next tile resident; reads done
        cur ^= 1;
    }
#undef STAGE

    // C/D layout: col = wc + n*16 + fr, row = wr + m*16 + fq*4 + j   [m89-verified]
    if constexpr (MODE == 0) {
        #pragma unroll
        for (int m = 0; m < 4; m++)
            #pragma unroll
            for (int n = 0; n < 4; n++) {
                const int col = bn + wc + n * 16 + fr;
                #pragma unroll
                for (int j = 0; j < 4; j++)
                    Cf[(size_t)(bm + wr + m * 16 + fq * 4 + j) * ldc + col] = acc[m][n][j];
            }
    } else if constexpr (MODE == 1) {
        #pragma unroll
        for (int m = 0; m < 4; m++)
            #pragma unroll
            for (int n = 0; n < 4; n++) {
                const int col = bn + wc + n * 16 + fr;
                if (col < 2112) {
                    #pragma unroll
                    for (int j = 0; j < 4; j++)
                        Cf[(size_t)(bm + wr + m * 16 + fq * 4 + j) * 2112 + col] = acc[m][n][j];
                }
            }
    } else if constexpr (MODE == 2) {
        #pragma unroll
        for (int n = 0; n < 4; n++) {
            const int col = bn + wc + n * 16 + fr;    // 0..3071
            const int h = col / DQK, d = col % DQK;
            #pragma unroll
            for (int m = 0; m < 4; m++) {
                #pragma unroll
                for (int j = 0; j < 4; j++) {
                    const int row = bm + wr + m * 16 + fq * 4 + j;
                    const int s = row & (SEQ - 1), b = row >> 11;
                    float v = acc[m][n][j];
                    if (d >= DVDIM) {
                        const int j5 = d - DVDIM;                 // 0..63
                        const float partner = acc[m][n ^ 2][j];   // col ^ 32, same head
                        const float rot = (j5 < 32) ? -partner : partner;
                        v = v * cosb[s * 64 + j5] + rot * sinb[s * 64 + j5];
                    }
                    O1[((size_t)(b * NHEADS + h) * SEQ + s) * DQK + d] = f2b(v);
                }
            }
        }
    } else if constexpr (MODE == 3) {
        #pragma unroll
        for (int n = 0; n < 4; n++) {
            const int col = bn + wc + n * 16 + fr;    // 0..2047 (k_nope features)
            const int h = col >> 7, d = col & 127;
            #pragma unroll
            for (int m = 0; m < 4; m++) {
                #pragma unroll
                for (int j = 0; j < 4; j++) {
                    const int row = bm + wr + m * 16 + fq * 4 + j;
                    const int s = row & (SEQ - 1);
                    const int bh = (row >> 11) * NHEADS + h;
                    O1[((size_t)bh * SEQ + s) * DQK + d] = f2b(acc[m][n][j]);
                }
            }
        }
    } else {  // MODE 4: V^T
        #pragma unroll
        for (int n = 0; n < 4; n++) {
            const int col = bn + wc + n * 16 + fr;    // 0..4095 (s rows)
            const int b = col >> 11, s = col & (SEQ - 1);
            #pragma unroll
            for (int m = 0; m < 4; m++) {
                #pragma unroll
                for (int j = 0; j < 4; j++) {
                    const int vf = bm + wr + m * 16 + fq * 4 + j;   // 0..2047
                    const int h = vf >> 7, dv = vf & 127;
                    O2[((size_t)(b * NHEADS + h) * DVDIM + dv) * SEQ + s] = f2b(acc[m][n][j]);
                }
            }
        }
    }
}

// ---------------- RMSNorm: fp32 in (row stride instride) -> bf16 out (tight) ----
__global__ __launch_bounds__(256) void rmsnorm_bf(const float* __restrict__ x,
                                                  const float* __restrict__ w,
                                                  unsigned short* __restrict__ o,
                                                  int ncols, int instride) {
    const float* xr = x + (size_t)blockIdx.x * instride;
    unsigned short* orow = o + (size_t)blockIdx.x * ncols;
    const int tid = threadIdx.x;
    float ss = 0.f;
    for (int c = tid * 4; c < ncols; c += 1024) {
        float4 v = ld4(xr + c);
        ss += v.x * v.x + v.y * v.y + v.z * v.z + v.w * v.w;
    }
    #pragma unroll
    for (int d = 32; d > 0; d >>= 1) ss += __shfl_down(ss, d);
    __shared__ float wsum[4];
    if ((tid & 63) == 0) wsum[tid >> 6] = ss;
    __syncthreads();
    float total = wsum[0] + wsum[1] + wsum[2] + wsum[3];
    float scale = 1.0f / sqrtf(total / (float)ncols + 1e-6f);
    for (int c = tid * 4; c < ncols; c += 1024) {
        float4 v = ld4(xr + c);
        short4v t;
        t[0] = (short)f2b(v.x * scale * w[c + 0]);
        t[1] = (short)f2b(v.y * scale * w[c + 1]);
        t[2] = (short)f2b(v.z * scale * w[c + 2]);
        t[3] = (short)f2b(v.w * scale * w[c + 3]);
        *(short4v*)&orow[c] = t;
    }
}

// ---------------- RoPE cos/sin table (SEQ x 64) ----------
__global__ void rope_table(float* __restrict__ cost, float* __restrict__ sint) {
    int s = blockIdx.x, j = threadIdx.x;
    int i = j & 31;
    float inv = 1.0f / powf(10000.0f, (float)i * (1.0f / 32.0f));
    float ang = (float)s * inv;
    cost[s * 64 + j] = cosf(ang);
    sint[s * 64 + j] = sinf(ang);
}

// ---------------- k_rope: rope(qkva cols 2048..2111) -> kbf[..][128..191], bcast 16 heads
__global__ void rope_k_bcast(const float* __restrict__ qkva,
                             const float* __restrict__ cost,
                             const float* __restrict__ sint,
                             unsigned short* __restrict__ kbf) {
    const int r = blockIdx.x;        // 0..4095
    const int j = threadIdx.x;       // 0..63
    const int b = r >> 11, s = r & (SEQ - 1);
    const float* base = qkva + (size_t)r * 2112 + 2048;
    const float x = base[j];
    const float rot = (j < 32) ? -base[j + 32] : base[j - 32];
    const unsigned short v = f2b(x * cost[s * 64 + j] + rot * sint[s * 64 + j]);
    #pragma unroll
    for (int h = 0; h < NHEADS; h++)
        kbf[((size_t)(b * NHEADS + h) * SEQ + s) * DQK + DVDIM + j] = v;
}

// =====================================================================
// bf16-MFMA flash attention (causal, online softmax, fp32 accum, bf16 out)
// Work-balanced pairs + register double-buffered K/V staging + XCD swizzle
// (4 heads per XCD -> K/V L2-resident) + setprio around MFMA clusters.
// =====================================================================
__global__ __launch_bounds__(256, 2) void flash_mfma(const unsigned short* __restrict__ qbf,
                                                     const unsigned short* __restrict__ kbf,
                                                     const unsigned short* __restrict__ vbfT,
                                                     unsigned short* __restrict__ attn) {
    __shared__ unsigned short Ks[64][200];
    __shared__ unsigned short Vs[128][72];
    __shared__ unsigned short Ps[4][16][72];

    // XCD-aware swizzle: 512 blocks; lin%8 = XCD; give each XCD 4 whole bh.
    const int lin = blockIdx.x;
    const int xcd = lin & 7;
    const int idx = lin >> 3;                 // 0..63
    const int bh = xcd * 4 + (idx >> 4);      // 4 heads per XCD
    const int bx = idx & 15;                  // q-tile pair
    const int b = bh >> 4, h = bh & 15;
    const int tid = threadIdx.x;
    const int w = tid >> 6, lane = tid & 63;
    const int fr = lane & 15, fq = lane >> 4;

    const unsigned short* Qh = qbf + ((size_t)bh * SEQ) * DQK;
    const unsigned short* Kh = kbf + ((size_t)bh * SEQ) * DQK;
    const unsigned short* Vh = vbfT + ((size_t)bh * 128) * SEQ;

    short8 kreg[6], vreg[4];
    #pragma unroll
    for (int u = 0; u < 6; u++) {
        int i = tid + u * 256;
        int row = i / 24, c = (i % 24) * 8;
        kreg[u] = *(const short8*)(Kh + (size_t)row * DQK + c);
    }
    #pragma unroll
    for (int u = 0; u < 4; u++) {
        int i = tid + u * 256;
        int row = i >> 3, c = (i & 7) * 8;
        vreg[u] = *(const short8*)(Vh + (size_t)row * SEQ + c);
    }

    #pragma unroll 1
    for (int pass = 0; pass < 2; pass++) {
        const int qt = pass ? (NTQ - 1 - bx) : bx;
        const int q0 = qt * 64;

        short8 qf[6];
        {
            const unsigned short* qrow = Qh + (size_t)(q0 + w * 16 + fr) * DQK;
            #pragma unroll
            for (int kw = 0; kw < 6; kw++)
                qf[kw] = *(const short8*)(qrow + kw * 32 + fq * 8);
        }

        f32x4 acc[8];
        #pragma unroll
        for (int n = 0; n < 8; n++) acc[n] = (f32x4)0.0f;
        float mrow[4], lrow[4];
        #pragma unroll
        for (int j = 0; j < 4; j++) { mrow[j] = -3.0e38f; lrow[j] = 0.0f; }

        #pragma unroll 1
        for (int t = 0; t <= qt; t++) {
            __syncthreads();
            #pragma unroll
            for (int u = 0; u < 6; u++) {
                int i = tid + u * 256;
                int row = i / 24, c = (i % 24) * 8;
                *(short8*)&Ks[row][c] = kreg[u];
            }
            #pragma unroll
            for (int u = 0; u < 4; u++) {
                int i = tid + u * 256;
                int row = i >> 3, c = (i & 7) * 8;
                *(short8*)&Vs[row][c] = vreg[u];
            }
            __syncthreads();

            const int nt = (t < qt) ? (t + 1) : (pass == 0 ? 0 : -1);
            if (nt >= 0) {
                const int kt0n = nt * 64;
                #pragma unroll
                for (int u = 0; u < 6; u++) {
                    int i = tid + u * 256;
                    int row = i / 24, c = (i % 24) * 8;
                    kreg[u] = *(const short8*)(Kh + (size_t)(kt0n + row) * DQK + c);
                }
                #pragma unroll
                for (int u = 0; u < 4; u++) {
                    int i = tid + u * 256;
                    int row = i >> 3, c = (i & 7) * 8;
                    vreg[u] = *(const short8*)(Vh + (size_t)row * SEQ + kt0n + c);
                }
            }

            f32x4 sfr[4];
            #pragma unroll
            for (int n = 0; n < 4; n++) sfr[n] = (f32x4)0.0f;
            __builtin_amdgcn_s_setprio(1);
            #pragma unroll
            for (int kw = 0; kw < 6; kw++) {
                #pragma unroll
                for (int n = 0; n < 4; n++) {
                    short8 kf = *(const short8*)&Ks[n * 16 + fr][kw * 32 + fq * 8];
                    sfr[n] = __builtin_amdgcn_mfma_f32_16x16x32_bf16(qf[kw], kf, sfr[n], 0, 0, 0);
                }
            }
            __builtin_amdgcn_s_setprio(0);

            const bool diag = (t == qt);
            float pv[4][4];
            float mnew[4];
            #pragma unroll
            for (int j = 0; j < 4; j++) mnew[j] = mrow[j];
            #pragma unroll
            for (int n = 0; n < 4; n++) {
                #pragma unroll
                for (int j = 0; j < 4; j++) {
                    float s = sfr[n][j] * SCALING;
                    if (diag && (n * 16 + fr > w * 16 + fq * 4 + j)) s = -3.0e38f;
                    pv[n][j] = s;
                    mnew[j] = fmaxf(mnew[j], s);
                }
            }
            #pragma unroll
            for (int j = 0; j < 4; j++) {
                mnew[j] = fmaxf(mnew[j], __shfl_xor(mnew[j], 1));
                mnew[j] = fmaxf(mnew[j], __shfl_xor(mnew[j], 2));
                mnew[j] = fmaxf(mnew[j], __shfl_xor(mnew[j], 4));
                mnew[j] = fmaxf(mnew[j], __shfl_xor(mnew[j], 8));
            }
            float es[4], psum[4];
            #pragma unroll
            for (int j = 0; j < 4; j++) {
                es[j] = __expf(mrow[j] - mnew[j]);
                psum[j] = 0.0f;
            }
            #pragma unroll
            for (int n = 0; n < 4; n++) {
                #pragma unroll
                for (int j = 0; j < 4; j++) {
                    float p = __expf(pv[n][j] - mnew[j]);
                    pv[n][j] = p;
                    psum[j] += p;
                }
            }
            #pragma unroll
            for (int j = 0; j < 4; j++) {
                psum[j] += __shfl_xor(psum[j], 1);
                psum[j] += __shfl_xor(psum[j], 2);
                psum[j] += __shfl_xor(psum[j], 4);
                psum[j] += __shfl_xor(psum[j], 8);
                lrow[j] = lrow[j] * es[j] + psum[j];
                mrow[j] = mnew[j];
            }
            #pragma unroll
            for (int n = 0; n < 8; n++) {
                #pragma unroll
                for (int j = 0; j < 4; j++) acc[n][j] *= es[j];
            }
            #pragma unroll
            for (int n = 0; n < 4; n++) {
                #pragma unroll
                for (int j = 0; j < 4; j++)
                    Ps[w][fq * 4 + j][n * 16 + fr] = f2b(pv[n][j]);
            }
            __builtin_amdgcn_s_setprio(1);
            #pragma unroll
            for (int tt = 0; tt < 2; tt++) {
                short8 pa = *(const short8*)&Ps[w][fr][tt * 32 + fq * 8];
                #pragma unroll
                for (int n = 0; n < 8; n++) {
                    short8 vf = *(const short8*)&Vs[n * 16 + fr][tt * 32 + fq * 8];
                    acc[n] = __builtin_amdgcn_mfma_f32_16x16x32_bf16(pa, vf, acc[n], 0, 0, 0);
                }
            }
            __builtin_amdgcn_s_setprio(0);
        }

        // epilogue: bf16 attn [row][h*128 + dv]
        #pragma unroll
        for (int j = 0; j < 4; j++) {
            const float inv = 1.0f / lrow[j];
            unsigned short* orow = attn + (size_t)(b * SEQ + q0 + w * 16 + fq * 4 + j) * (NHEADS * DVDIM) + h * DVDIM;
            #pragma unroll
            for (int n = 0; n < 8; n++)
                orow[n * 16 + fr] = f2b(acc[n][j] * inv);
        }
    }
}

extern "C" void kernel_launch(void* const* d_in, const int* in_sizes, int n_in,
                              void* d_out, int out_size, void* d_ws, size_t ws_size,
                              hipStream_t stream) {
    const float* hidden   = (const float*)d_in[0];
    const float* q_a_w    = (const float*)d_in[1];
    const float* q_a_ln_w = (const float*)d_in[2];
    const float* q_b_w    = (const float*)d_in[3];
    const float* kv_a_w   = (const float*)d_in[4];
    const float* kv_a_ln_w= (const float*)d_in[5];
    const float* kv_b_w   = (const float*)d_in[6];
    const float* o_w      = (const float*)d_in[7];
    float* out = (float*)d_out;

    char* base = (char*)d_ws;
    size_t off = 0;
    auto alloc = [&](size_t bytes) -> void* {
        void* p = base + off;
        off += (bytes + 255) & ~(size_t)255;
        return p;
    };
    float* qkva          = (float*)alloc((size_t)MROWS * 2112 * 4);            // 34.6MB
    float* cosb          = (float*)alloc((size_t)SEQ * 64 * 4);
    float* sinb          = (float*)alloc((size_t)SEQ * 64 * 4);
    unsigned short* hbf  = (unsigned short*)alloc((size_t)MROWS * HDIM * 2);       // 16.8MB
    unsigned short* w_qa = (unsigned short*)alloc((size_t)QLORA * HDIM * 2);       // 6.3MB
    unsigned short* w_qb = (unsigned short*)alloc((size_t)3072 * QLORA * 2);       // 9.4MB
    unsigned short* w_kva= (unsigned short*)alloc((size_t)576 * HDIM * 2);         // 2.4MB
    unsigned short* w_kvb= (unsigned short*)alloc((size_t)4096 * KVLORA * 2);      // 4.2MB
    unsigned short* w_o  = (unsigned short*)alloc((size_t)HDIM * 2048 * 2);        // 8.4MB
    unsigned short* qabf = (unsigned short*)alloc((size_t)MROWS * QLORA * 2);      // 12.6MB
    unsigned short* ckvbf= (unsigned short*)alloc((size_t)MROWS * KVLORA * 2);     // 4.2MB
    unsigned short* qbf  = (unsigned short*)alloc((size_t)32 * SEQ * DQK * 2);     // 25.2MB
    unsigned short* kbf  = (unsigned short*)alloc((size_t)32 * SEQ * DQK * 2);     // 25.2MB
    unsigned short* vbfT = (unsigned short*)alloc((size_t)32 * DVDIM * SEQ * 2);   // 16.8MB
    unsigned short* attnbf=(unsigned short*)alloc((size_t)MROWS * 2048 * 2);       // 16.8MB
    // total ~184MB (<= proven 186.6MB footprint)

    // bf16 conversions
    cvt_bf<<<4096, 256, 0, stream>>>(hidden, hbf, 1048576);
    cvt_bf<<<1536, 256, 0, stream>>>(q_a_w,  w_qa, 393216);
    cvt_bf<<<2304, 256, 0, stream>>>(q_b_w,  w_qb, 589824);
    cvt_bf<<< 576, 256, 0, stream>>>(kv_a_w, w_kva, 147456);
    cvt_bf<<<1024, 256, 0, stream>>>(kv_b_w, w_kvb, 262144);
    cvt_bf<<<2048, 256, 0, stream>>>(o_w,    w_o,  524288);
    rope_table<<<SEQ, 64, 0, stream>>>(cosb, sinb);

    // fused q_a | kv_a = hidden @ [q_a_w; kv_a_w].T -> fp32 qkva [4096][2112]
    gemm_bf16<1><<<dim3(17, 32), 256, 0, stream>>>(hbf, HDIM, w_qa, w_kva,
                                                   qkva, 2112, nullptr, nullptr,
                                                   nullptr, nullptr, HDIM);
    // rmsnorms -> bf16 activations
    rmsnorm_bf<<<MROWS, 256, 0, stream>>>(qkva, q_a_ln_w, qabf, QLORA, 2112);
    rmsnorm_bf<<<MROWS, 256, 0, stream>>>(qkva + 1536, kv_a_ln_w, ckvbf, KVLORA, 2112);
    // q = norm(q_a) @ q_b_w.T -> qbf (RoPE fused)
    gemm_bf16<2><<<dim3(24, 32), 256, 0, stream>>>(qabf, QLORA, w_qb, nullptr,
                                                   nullptr, 0, qbf, nullptr,
                                                   cosb, sinb, QLORA);
    // k_nope = norm(c_kv) @ kv_b_w(nope rows).T -> kbf
    gemm_bf16<3><<<dim3(16, 32), 256, 0, stream>>>(ckvbf, KVLORA, w_kvb, nullptr,
                                                   nullptr, 0, kbf, nullptr,
                                                   nullptr, nullptr, KVLORA);
    // V^T = kv_b_w(v rows) @ norm(c_kv).T -> vbfT (natively transposed output)
    gemm_bf16<4><<<dim3(32, 16), 256, 0, stream>>>(w_kvb, KVLORA, ckvbf, nullptr,
                                                   nullptr, 0, nullptr, vbfT,
                                                   nullptr, nullptr, KVLORA);
    // roped k_rope broadcast into kbf cols 128..191
    rope_k_bcast<<<MROWS, 64, 0, stream>>>(qkva, cosb, sinb, kbf);
    // flash attention -> bf16 attn
    flash_mfma<<<512, 256, 0, stream>>>(qbf, kbf, vbfT, attnbf);
    // out = attn @ o_w.T -> fp32 d_out
    gemm_bf16<0><<<dim3(16, 32), 256, 0, stream>>>(attnbf, 2048, w_o, nullptr,
                                                   out, 2048, nullptr, nullptr,
                                                   nullptr, nullptr, 2048);
}

// Round 8
// 488.321 us; speedup vs baseline: 7.6035x; 1.0298x over previous
//
#include <hip/hip_runtime.h>
#include <hip/hip_bf16.h>
#include <math.h>
#include <stdint.h>

// Problem constants (DeepseekV3 MLA prefill)
#define NHEADS 16
#define DQK 192
#define DVDIM 128
#define SEQ 2048
#define BATCH 2
#define MROWS 4096   // BATCH*SEQ
#define HDIM 2048
#define QLORA 1536
#define KVLORA 512
#define SCALING 0.07216878364870323f  // 192^-0.5
#define NTQ 32       // SEQ / 64 q-tiles

typedef __attribute__((ext_vector_type(8))) short short8;
typedef __attribute__((ext_vector_type(4))) short short4v;
typedef __attribute__((ext_vector_type(4))) float f32x4;

__device__ __forceinline__ float4 ld4(const float* p) {
    return *reinterpret_cast<const float4*>(p);
}
__device__ __forceinline__ unsigned short f2b(float x) {
    __hip_bfloat16 h = __float2bfloat16(x);   // RNE
    return __builtin_bit_cast(unsigned short, h);
}
// async global->LDS, 16B per lane; LDS dest = wave-uniform base, HW adds lane*16.
__device__ __forceinline__ void gload16(const void* g, void* l) {
    typedef const __attribute__((address_space(1))) unsigned int ga_t;
    typedef __attribute__((address_space(3))) unsigned int ls_t;
    __builtin_amdgcn_global_load_lds((ga_t*)(uintptr_t)g, (ls_t*)(uintptr_t)l, 16, 0, 0);
}

// ---------------- flat fp32 -> bf16 convert (8 elems/thread) ----------------
__global__ __launch_bounds__(256) void cvt_bf(const float* __restrict__ in,
                                              unsigned short* __restrict__ o, int n8) {
    int i = blockIdx.x * 256 + threadIdx.x;
    if (i >= n8) return;
    float4 a = ld4(in + (size_t)i * 8), b = ld4(in + (size_t)i * 8 + 4);
    short8 t;
    t[0] = (short)f2b(a.x); t[1] = (short)f2b(a.y); t[2] = (short)f2b(a.z); t[3] = (short)f2b(a.w);
    t[4] = (short)f2b(b.x); t[5] = (short)f2b(b.y); t[6] = (short)f2b(b.z); t[7] = (short)f2b(b.w);
    *(short8*)(o + (size_t)i * 8) = t;
}

// =====================================================================
// Pure-bf16 MFMA GEMM, 128x128 tile, BK=32, 4 waves.
// 3-buffer LDS pipeline with counted vmcnt (never drains to 0 in steady
// state) + raw s_barrier: each tile's global_load_lds has ~2 MFMA phases
// to complete.  C = A[M,K] @ W[N,K]^T.  MODE as in round 7.
// =====================================================================
template <int MODE>
__global__ __launch_bounds__(256) void gemm_bf16(
        const unsigned short* __restrict__ A, int lda,
        const unsigned short* __restrict__ W, const unsigned short* __restrict__ W2,
        float* __restrict__ Cf, int ldc,
        unsigned short* __restrict__ O1, unsigned short* __restrict__ O2,
        const float* __restrict__ cosb, const float* __restrict__ sinb,
        int K) {
    __shared__ unsigned short As[3][128 * 32];   // 3 x 8KB
    __shared__ unsigned short Bs[3][128 * 32];

    const int tid = threadIdx.x;
    const int bm = blockIdx.y * 128, bn = blockIdx.x * 128;
    const int w = tid >> 6, lane = tid & 63;
    const int wr = (w >> 1) * 64, wc = (w & 1) * 64;
    const int fr = lane & 15, fq = lane >> 4;

    // staging coords: wave w stages rows w*32..+31 (two 16-row chunks)
    const int r0 = w * 32 + (lane >> 2);
    const int c0 = (lane & 3) * 8;

    const unsigned short* Ag0;
    if constexpr (MODE == 4) {
        Ag0 = A + (size_t)((bm >> 7) * 256 + 128 + r0) * lda + c0;   // v-feature remap
    } else {
        Ag0 = A + (size_t)(bm + r0) * lda + c0;
    }
    const unsigned short* Ag1 = Ag0 + (size_t)16 * lda;

    const unsigned short* Wg0;
    const unsigned short* Wg1;
    if constexpr (MODE == 1) {
        if (bn < 1536) {
            Wg0 = W + (size_t)(bn + r0) * K + c0;
            Wg1 = Wg0 + (size_t)16 * K;
        } else {
            int br0 = bn - 1536 + r0;      if (br0 > 575) br0 = 575;
            int br1 = bn - 1536 + r0 + 16; if (br1 > 575) br1 = 575;
            Wg0 = W2 + (size_t)br0 * K + c0;
            Wg1 = W2 + (size_t)br1 * K + c0;
        }
    } else if constexpr (MODE == 3) {
        Wg0 = W + (size_t)((bn >> 7) * 256 + r0) * K + c0;           // k_nope remap
        Wg1 = Wg0 + (size_t)16 * K;
    } else {
        Wg0 = W + (size_t)(bn + r0) * K + c0;
        Wg1 = Wg0 + (size_t)16 * K;
    }

#define STAGE(buf, koff) do { \
        gload16(Ag0 + (koff), &As[buf][(w * 32) * 32]); \
        gload16(Ag1 + (koff), &As[buf][(w * 32 + 16) * 32]); \
        gload16(Wg0 + (koff), &Bs[buf][(w * 32) * 32]); \
        gload16(Wg1 + (koff), &Bs[buf][(w * 32 + 16) * 32]); \
    } while (0)

    f32x4 acc[4][4];
    #pragma unroll
    for (int m = 0; m < 4; m++)
        #pragma unroll
        for (int n = 0; n < 4; n++) acc[m][n] = (f32x4)0.0f;

    const int NT = K >> 5;         // >= 16 for all our K
    STAGE(0, 0);
    STAGE(1, 32);
    int cb = 0;
    for (int t = 0; t < NT; t++) {
        // wait for tile t's 4 loads (allow the newest 4 = tile t+1's to fly)
        if (t == NT - 1) asm volatile("s_waitcnt vmcnt(0)" ::: "memory");
        else             asm volatile("s_waitcnt vmcnt(4)" ::: "memory");
        __builtin_amdgcn_s_barrier();
        __builtin_amdgcn_sched_barrier(0);

        if (t + 2 < NT) {
            int nb = cb + 2; if (nb >= 3) nb -= 3;
            STAGE(nb, (t + 2) * 32);
        }

        short8 af[4], bfr[4];
        #pragma unroll
        for (int m = 0; m < 4; m++)
            af[m] = *(const short8*)&As[cb][(wr + m * 16 + fr) * 32 + fq * 8];
        #pragma unroll
        for (int n = 0; n < 4; n++)
            bfr[n] = *(const short8*)&Bs[cb][(wc + n * 16 + fr) * 32 + fq * 8];
        #pragma unroll
        for (int m = 0; m < 4; m++)
            #pragma unroll
            for (int n = 0; n < 4; n++)
                acc[m][n] = __builtin_amdgcn_mfma_f32_16x16x32_bf16(af[m], bfr[n], acc[m][n], 0, 0, 0);

        cb++; if (cb >= 3) cb = 0;
    }
#undef STAGE

    // C/D layout: col = wc + n*16 + fr, row = wr + m*16 + fq*4 + j   [m89-verified]
    if constexpr (MODE == 0) {
        #pragma unroll
        for (int m = 0; m < 4; m++)
            #pragma unroll
            for (int n = 0; n < 4; n++) {
                const int col = bn + wc + n * 16 + fr;
                #pragma unroll
                for (int j = 0; j < 4; j++)
                    Cf[(size_t)(bm + wr + m * 16 + fq * 4 + j) * ldc + col] = acc[m][n][j];
            }
    } else if constexpr (MODE == 1) {
        #pragma unroll
        for (int m = 0; m < 4; m++)
            #pragma unroll
            for (int n = 0; n < 4; n++) {
                const int col = bn + wc + n * 16 + fr;
                if (col < 2112) {
                    #pragma unroll
                    for (int j = 0; j < 4; j++)
                        Cf[(size_t)(bm + wr + m * 16 + fq * 4 + j) * 2112 + col] = acc[m][n][j];
                }
            }
    } else if constexpr (MODE == 2) {
        #pragma unroll
        for (int n = 0; n < 4; n++) {
            const int col = bn + wc + n * 16 + fr;    // 0..3071
            const int h = col / DQK, d = col % DQK;
            #pragma unroll
            for (int m = 0; m < 4; m++) {
                #pragma unroll
                for (int j = 0; j < 4; j++) {
                    const int row = bm + wr + m * 16 + fq * 4 + j;
                    const int s = row & (SEQ - 1), b = row >> 11;
                    float v = acc[m][n][j];
                    if (d >= DVDIM) {
                        const int j5 = d - DVDIM;                 // 0..63
                        const float partner = acc[m][n ^ 2][j];   // col ^ 32, same head
                        const float rot = (j5 < 32) ? -partner : partner;
                        v = v * cosb[s * 64 + j5] + rot * sinb[s * 64 + j5];
                    }
                    O1[((size_t)(b * NHEADS + h) * SEQ + s) * DQK + d] = f2b(v);
                }
            }
        }
    } else if constexpr (MODE == 3) {
        #pragma unroll
        for (int n = 0; n < 4; n++) {
            const int col = bn + wc + n * 16 + fr;    // 0..2047 (k_nope features)
            const int h = col >> 7, d = col & 127;
            #pragma unroll
            for (int m = 0; m < 4; m++) {
                #pragma unroll
                for (int j = 0; j < 4; j++) {
                    const int row = bm + wr + m * 16 + fq * 4 + j;
                    const int s = row & (SEQ - 1);
                    const int bh = (row >> 11) * NHEADS + h;
                    O1[((size_t)bh * SEQ + s) * DQK + d] = f2b(acc[m][n][j]);
                }
            }
        }
    } else {  // MODE 4: V^T
        #pragma unroll
        for (int n = 0; n < 4; n++) {
            const int col = bn + wc + n * 16 + fr;    // 0..4095 (s rows)
            const int b = col >> 11, s = col & (SEQ - 1);
            #pragma unroll
            for (int m = 0; m < 4; m++) {
                #pragma unroll
                for (int j = 0; j < 4; j++) {
                    const int vf = bm + wr + m * 16 + fq * 4 + j;   // 0..2047
                    const int h = vf >> 7, dv = vf & 127;
                    O2[((size_t)(b * NHEADS + h) * DVDIM + dv) * SEQ + s] = f2b(acc[m][n][j]);
                }
            }
        }
    }
}

// ---------------- RMSNorm: fp32 in (row stride instride) -> bf16 out (tight) ----
__global__ __launch_bounds__(256) void rmsnorm_bf(const float* __restrict__ x,
                                                  const float* __restrict__ w,
                                                  unsigned short* __restrict__ o,
                                                  int ncols, int instride) {
    const float* xr = x + (size_t)blockIdx.x * instride;
    unsigned short* orow = o + (size_t)blockIdx.x * ncols;
    const int tid = threadIdx.x;
    float ss = 0.f;
    for (int c = tid * 4; c < ncols; c += 1024) {
        float4 v = ld4(xr + c);
        ss += v.x * v.x + v.y * v.y + v.z * v.z + v.w * v.w;
    }
    #pragma unroll
    for (int d = 32; d > 0; d >>= 1) ss += __shfl_down(ss, d);
    __shared__ float wsum[4];
    if ((tid & 63) == 0) wsum[tid >> 6] = ss;
    __syncthreads();
    float total = wsum[0] + wsum[1] + wsum[2] + wsum[3];
    float scale = 1.0f / sqrtf(total / (float)ncols + 1e-6f);
    for (int c = tid * 4; c < ncols; c += 1024) {
        float4 v = ld4(xr + c);
        short4v t;
        t[0] = (short)f2b(v.x * scale * w[c + 0]);
        t[1] = (short)f2b(v.y * scale * w[c + 1]);
        t[2] = (short)f2b(v.z * scale * w[c + 2]);
        t[3] = (short)f2b(v.w * scale * w[c + 3]);
        *(short4v*)&orow[c] = t;
    }
}

// ---------------- RoPE cos/sin table (SEQ x 64) ----------
__global__ void rope_table(float* __restrict__ cost, float* __restrict__ sint) {
    int s = blockIdx.x, j = threadIdx.x;
    int i = j & 31;
    float inv = 1.0f / powf(10000.0f, (float)i * (1.0f / 32.0f));
    float ang = (float)s * inv;
    cost[s * 64 + j] = cosf(ang);
    sint[s * 64 + j] = sinf(ang);
}

// ---------------- k_rope: rope(qkva cols 2048..2111) -> kbf[..][128..191], bcast 16 heads
__global__ void rope_k_bcast(const float* __restrict__ qkva,
                             const float* __restrict__ cost,
                             const float* __restrict__ sint,
                             unsigned short* __restrict__ kbf) {
    const int r = blockIdx.x;        // 0..4095
    const int j = threadIdx.x;       // 0..63
    const int b = r >> 11, s = r & (SEQ - 1);
    const float* base = qkva + (size_t)r * 2112 + 2048;
    const float x = base[j];
    const float rot = (j < 32) ? -base[j + 32] : base[j - 32];
    const unsigned short v = f2b(x * cost[s * 64 + j] + rot * sint[s * 64 + j]);
    #pragma unroll
    for (int h = 0; h < NHEADS; h++)
        kbf[((size_t)(b * NHEADS + h) * SEQ + s) * DQK + DVDIM + j] = v;
}

// =====================================================================
// bf16-MFMA flash attention (causal, online softmax, fp32 accum, bf16 out)
// Work-balanced pairs + reg double-buffered K/V + XCD swizzle + setprio
// + defer-max (T13, THR=8): skip O-rescale when tile max growth <= 8.
// =====================================================================
__global__ __launch_bounds__(256, 2) void flash_mfma(const unsigned short* __restrict__ qbf,
                                                     const unsigned short* __restrict__ kbf,
                                                     const unsigned short* __restrict__ vbfT,
                                                     unsigned short* __restrict__ attn) {
    __shared__ unsigned short Ks[64][200];
    __shared__ unsigned short Vs[128][72];
    __shared__ unsigned short Ps[4][16][72];

    // XCD-aware swizzle: 512 blocks; lin%8 = XCD; give each XCD 4 whole bh.
    const int lin = blockIdx.x;
    const int xcd = lin & 7;
    const int idx = lin >> 3;                 // 0..63
    const int bh = xcd * 4 + (idx >> 4);      // 4 heads per XCD
    const int bx = idx & 15;                  // q-tile pair
    const int b = bh >> 4, h = bh & 15;
    const int tid = threadIdx.x;
    const int w = tid >> 6, lane = tid & 63;
    const int fr = lane & 15, fq = lane >> 4;

    const unsigned short* Qh = qbf + ((size_t)bh * SEQ) * DQK;
    const unsigned short* Kh = kbf + ((size_t)bh * SEQ) * DQK;
    const unsigned short* Vh = vbfT + ((size_t)bh * 128) * SEQ;

    short8 kreg[6], vreg[4];
    #pragma unroll
    for (int u = 0; u < 6; u++) {
        int i = tid + u * 256;
        int row = i / 24, c = (i % 24) * 8;
        kreg[u] = *(const short8*)(Kh + (size_t)row * DQK + c);
    }
    #pragma unroll
    for (int u = 0; u < 4; u++) {
        int i = tid + u * 256;
        int row = i >> 3, c = (i & 7) * 8;
        vreg[u] = *(const short8*)(Vh + (size_t)row * SEQ + c);
    }

    #pragma unroll 1
    for (int pass = 0; pass < 2; pass++) {
        const int qt = pass ? (NTQ - 1 - bx) : bx;
        const int q0 = qt * 64;

        short8 qf[6];
        {
            const unsigned short* qrow = Qh + (size_t)(q0 + w * 16 + fr) * DQK;
            #pragma unroll
            for (int kw = 0; kw < 6; kw++)
                qf[kw] = *(const short8*)(qrow + kw * 32 + fq * 8);
        }

        f32x4 acc[8];
        #pragma unroll
        for (int n = 0; n < 8; n++) acc[n] = (f32x4)0.0f;
        float mrow[4], lrow[4];
        #pragma unroll
        for (int j = 0; j < 4; j++) { mrow[j] = -3.0e38f; lrow[j] = 0.0f; }

        #pragma unroll 1
        for (int t = 0; t <= qt; t++) {
            __syncthreads();
            #pragma unroll
            for (int u = 0; u < 6; u++) {
                int i = tid + u * 256;
                int row = i / 24, c = (i % 24) * 8;
                *(short8*)&Ks[row][c] = kreg[u];
            }
            #pragma unroll
            for (int u = 0; u < 4; u++) {
                int i = tid + u * 256;
                int row = i >> 3, c = (i & 7) * 8;
                *(short8*)&Vs[row][c] = vreg[u];
            }
            __syncthreads();

            const int nt = (t < qt) ? (t + 1) : (pass == 0 ? 0 : -1);
            if (nt >= 0) {
                const int kt0n = nt * 64;
                #pragma unroll
                for (int u = 0; u < 6; u++) {
                    int i = tid + u * 256;
                    int row = i / 24, c = (i % 24) * 8;
                    kreg[u] = *(const short8*)(Kh + (size_t)(kt0n + row) * DQK + c);
                }
                #pragma unroll
                for (int u = 0; u < 4; u++) {
                    int i = tid + u * 256;
                    int row = i >> 3, c = (i & 7) * 8;
                    vreg[u] = *(const short8*)(Vh + (size_t)row * SEQ + kt0n + c);
                }
            }

            f32x4 sfr[4];
            #pragma unroll
            for (int n = 0; n < 4; n++) sfr[n] = (f32x4)0.0f;
            __builtin_amdgcn_s_setprio(1);
            #pragma unroll
            for (int kw = 0; kw < 6; kw++) {
                #pragma unroll
                for (int n = 0; n < 4; n++) {
                    short8 kf = *(const short8*)&Ks[n * 16 + fr][kw * 32 + fq * 8];
                    sfr[n] = __builtin_amdgcn_mfma_f32_16x16x32_bf16(qf[kw], kf, sfr[n], 0, 0, 0);
                }
            }
            __builtin_amdgcn_s_setprio(0);

            const bool diag = (t == qt);
            float pv[4][4];
            float tmax[4];
            #pragma unroll
            for (int j = 0; j < 4; j++) tmax[j] = -3.0e38f;
            #pragma unroll
            for (int n = 0; n < 4; n++) {
                #pragma unroll
                for (int j = 0; j < 4; j++) {
                    float s = sfr[n][j] * SCALING;
                    if (diag && (n * 16 + fr > w * 16 + fq * 4 + j)) s = -3.0e38f;
                    pv[n][j] = s;
                    tmax[j] = fmaxf(tmax[j], s);
                }
            }
            #pragma unroll
            for (int j = 0; j < 4; j++) {
                tmax[j] = fmaxf(tmax[j], __shfl_xor(tmax[j], 1));
                tmax[j] = fmaxf(tmax[j], __shfl_xor(tmax[j], 2));
                tmax[j] = fmaxf(tmax[j], __shfl_xor(tmax[j], 4));
                tmax[j] = fmaxf(tmax[j], __shfl_xor(tmax[j], 8));
            }
            // defer-max: keep old running max when growth bounded (<= 8)
            bool defer[4];
            float mnew[4], es[4], psum[4];
            #pragma unroll
            for (int j = 0; j < 4; j++) {
                defer[j] = (tmax[j] - mrow[j] <= 8.0f);
                mnew[j] = defer[j] ? mrow[j] : tmax[j];
                es[j] = defer[j] ? 1.0f : __expf(mrow[j] - mnew[j]);
                psum[j] = 0.0f;
            }
            #pragma unroll
            for (int n = 0; n < 4; n++) {
                #pragma unroll
                for (int j = 0; j < 4; j++) {
                    float p = __expf(pv[n][j] - mnew[j]);
                    pv[n][j] = p;
                    psum[j] += p;
                }
            }
            #pragma unroll
            for (int j = 0; j < 4; j++) {
                psum[j] += __shfl_xor(psum[j], 1);
                psum[j] += __shfl_xor(psum[j], 2);
                psum[j] += __shfl_xor(psum[j], 4);
                psum[j] += __shfl_xor(psum[j], 8);
                lrow[j] = lrow[j] * es[j] + psum[j];
                mrow[j] = mnew[j];
            }
            const bool needresc = !(defer[0] && defer[1] && defer[2] && defer[3]);
            if (__any(needresc)) {
                #pragma unroll
                for (int n = 0; n < 8; n++) {
                    #pragma unroll
                    for (int j = 0; j < 4; j++) acc[n][j] *= es[j];
                }
            }
            #pragma unroll
            for (int n = 0; n < 4; n++) {
                #pragma unroll
                for (int j = 0; j < 4; j++)
                    Ps[w][fq * 4 + j][n * 16 + fr] = f2b(pv[n][j]);
            }
            __builtin_amdgcn_s_setprio(1);
            #pragma unroll
            for (int tt = 0; tt < 2; tt++) {
                short8 pa = *(const short8*)&Ps[w][fr][tt * 32 + fq * 8];
                #pragma unroll
                for (int n = 0; n < 8; n++) {
                    short8 vf = *(const short8*)&Vs[n * 16 + fr][tt * 32 + fq * 8];
                    acc[n] = __builtin_amdgcn_mfma_f32_16x16x32_bf16(pa, vf, acc[n], 0, 0, 0);
                }
            }
            __builtin_amdgcn_s_setprio(0);
        }

        // epilogue: bf16 attn [row][h*128 + dv]
        #pragma unroll
        for (int j = 0; j < 4; j++) {
            const float inv = 1.0f / lrow[j];
            unsigned short* orow = attn + (size_t)(b * SEQ + q0 + w * 16 + fq * 4 + j) * (NHEADS * DVDIM) + h * DVDIM;
            #pragma unroll
            for (int n = 0; n < 8; n++)
                orow[n * 16 + fr] = f2b(acc[n][j] * inv);
        }
    }
}

extern "C" void kernel_launch(void* const* d_in, const int* in_sizes, int n_in,
                              void* d_out, int out_size, void* d_ws, size_t ws_size,
                              hipStream_t stream) {
    const float* hidden   = (const float*)d_in[0];
    const float* q_a_w    = (const float*)d_in[1];
    const float* q_a_ln_w = (const float*)d_in[2];
    const float* q_b_w    = (const float*)d_in[3];
    const float* kv_a_w   = (const float*)d_in[4];
    const float* kv_a_ln_w= (const float*)d_in[5];
    const float* kv_b_w   = (const float*)d_in[6];
    const float* o_w      = (const float*)d_in[7];
    float* out = (float*)d_out;

    char* base = (char*)d_ws;
    size_t off = 0;
    auto alloc = [&](size_t bytes) -> void* {
        void* p = base + off;
        off += (bytes + 255) & ~(size_t)255;
        return p;
    };
    float* qkva          = (float*)alloc((size_t)MROWS * 2112 * 4);            // 34.6MB
    float* cosb          = (float*)alloc((size_t)SEQ * 64 * 4);
    float* sinb          = (float*)alloc((size_t)SEQ * 64 * 4);
    unsigned short* hbf  = (unsigned short*)alloc((size_t)MROWS * HDIM * 2);       // 16.8MB
    unsigned short* w_qa = (unsigned short*)alloc((size_t)QLORA * HDIM * 2);       // 6.3MB
    unsigned short* w_qb = (unsigned short*)alloc((size_t)3072 * QLORA * 2);       // 9.4MB
    unsigned short* w_kva= (unsigned short*)alloc((size_t)576 * HDIM * 2);         // 2.4MB
    unsigned short* w_kvb= (unsigned short*)alloc((size_t)4096 * KVLORA * 2);      // 4.2MB
    unsigned short* w_o  = (unsigned short*)alloc((size_t)HDIM * 2048 * 2);        // 8.4MB
    unsigned short* qabf = (unsigned short*)alloc((size_t)MROWS * QLORA * 2);      // 12.6MB
    unsigned short* ckvbf= (unsigned short*)alloc((size_t)MROWS * KVLORA * 2);     // 4.2MB
    unsigned short* qbf  = (unsigned short*)alloc((size_t)32 * SEQ * DQK * 2);     // 25.2MB
    unsigned short* kbf  = (unsigned short*)alloc((size_t)32 * SEQ * DQK * 2);     // 25.2MB
    unsigned short* vbfT = (unsigned short*)alloc((size_t)32 * DVDIM * SEQ * 2);   // 16.8MB
    unsigned short* attnbf=(unsigned short*)alloc((size_t)MROWS * 2048 * 2);       // 16.8MB
    // total ~184MB (<= proven 186.6MB footprint)

    // bf16 conversions
    cvt_bf<<<4096, 256, 0, stream>>>(hidden, hbf, 1048576);
    cvt_bf<<<1536, 256, 0, stream>>>(q_a_w,  w_qa, 393216);
    cvt_bf<<<2304, 256, 0, stream>>>(q_b_w,  w_qb, 589824);
    cvt_bf<<< 576, 256, 0, stream>>>(kv_a_w, w_kva, 147456);
    cvt_bf<<<1024, 256, 0, stream>>>(kv_b_w, w_kvb, 262144);
    cvt_bf<<<2048, 256, 0, stream>>>(o_w,    w_o,  524288);
    rope_table<<<SEQ, 64, 0, stream>>>(cosb, sinb);

    // fused q_a | kv_a = hidden @ [q_a_w; kv_a_w].T -> fp32 qkva [4096][2112]
    gemm_bf16<1><<<dim3(17, 32), 256, 0, stream>>>(hbf, HDIM, w_qa, w_kva,
                                                   qkva, 2112, nullptr, nullptr,
                                                   nullptr, nullptr, HDIM);
    // rmsnorms -> bf16 activations
    rmsnorm_bf<<<MROWS, 256, 0, stream>>>(qkva, q_a_ln_w, qabf, QLORA, 2112);
    rmsnorm_bf<<<MROWS, 256, 0, stream>>>(qkva + 1536, kv_a_ln_w, ckvbf, KVLORA, 2112);
    // q = norm(q_a) @ q_b_w.T -> qbf (RoPE fused)
    gemm_bf16<2><<<dim3(24, 32), 256, 0, stream>>>(qabf, QLORA, w_qb, nullptr,
                                                   nullptr, 0, qbf, nullptr,
                                                   cosb, sinb, QLORA);
    // k_nope = norm(c_kv) @ kv_b_w(nope rows).T -> kbf
    gemm_bf16<3><<<dim3(16, 32), 256, 0, stream>>>(ckvbf, KVLORA, w_kvb, nullptr,
                                                   nullptr, 0, kbf, nullptr,
                                                   nullptr, nullptr, KVLORA);
    // V^T = kv_b_w(v rows) @ norm(c_kv).T -> vbfT (natively transposed output)
    gemm_bf16<4><<<dim3(32, 16), 256, 0, stream>>>(w_kvb, KVLORA, ckvbf, nullptr,
                                                   nullptr, 0, nullptr, vbfT,
                                                   nullptr, nullptr, KVLORA);
    // roped k_rope broadcast into kbf cols 128..191
    rope_k_bcast<<<MROWS, 64, 0, stream>>>(qkva, cosb, sinb, kbf);
    // flash attention -> bf16 attn
    flash_mfma<<<512, 256, 0, stream>>>(qbf, kbf, vbfT, attnbf);
    // out = attn @ o_w.T -> fp32 d_out
    gemm_bf16<0><<<dim3(16, 32), 256, 0, stream>>>(attnbf, 2048, w_o, nullptr,
                                                   out, 2048, nullptr, nullptr,
                                                   nullptr, nullptr, 2048);
}

// Round 9
// 465.852 us; speedup vs baseline: 7.9702x; 1.0482x over previous
//
#include <hip/hip_runtime.h>
#include <hip/hip_bf16.h>
#include <math.h>
#include <stdint.h>

// Problem constants (DeepseekV3 MLA prefill)
#define NHEADS 16
#define DQK 192
#define DVDIM 128
#define SEQ 2048
#define BATCH 2
#define MROWS 4096   // BATCH*SEQ
#define HDIM 2048
#define QLORA 1536
#define KVLORA 512
#define SCALING 0.07216878364870323f  // 192^-0.5
#define NTQ 32       // SEQ / 64 q-tiles

typedef __attribute__((ext_vector_type(8))) short short8;
typedef __attribute__((ext_vector_type(4))) short short4v;
typedef __attribute__((ext_vector_type(4))) float f32x4;

__device__ __forceinline__ float4 ld4(const float* p) {
    return *reinterpret_cast<const float4*>(p);
}
__device__ __forceinline__ unsigned short f2b(float x) {
    __hip_bfloat16 h = __float2bfloat16(x);   // RNE
    return __builtin_bit_cast(unsigned short, h);
}
// async global->LDS, 16B per lane; LDS dest = wave-uniform base, HW adds lane*16.
__device__ __forceinline__ void gload16(const void* g, void* l) {
    typedef const __attribute__((address_space(1))) unsigned int ga_t;
    typedef __attribute__((address_space(3))) unsigned int ls_t;
    __builtin_amdgcn_global_load_lds((ga_t*)(uintptr_t)g, (ls_t*)(uintptr_t)l, 16, 0, 0);
}

// ---------------- fused fp32 -> bf16 convert for all 6 tensors ----------------
// segments in units of 8 elements; total 2,965,504 -> 11,584 blocks of 256.
#define S0 1048576   // hidden  4096x2048
#define S1 393216    // q_a_w   1536x2048
#define S2 589824    // q_b_w   3072x1536
#define S3 147456    // kv_a_w  576x2048
#define S4 262144    // kv_b_w  4096x512
#define S5 524288    // o_w     2048x2048
__global__ __launch_bounds__(256) void cvt_all(
        const float* __restrict__ i0, const float* __restrict__ i1,
        const float* __restrict__ i2, const float* __restrict__ i3,
        const float* __restrict__ i4, const float* __restrict__ i5,
        unsigned short* __restrict__ o0, unsigned short* __restrict__ o1,
        unsigned short* __restrict__ o2, unsigned short* __restrict__ o3,
        unsigned short* __restrict__ o4, unsigned short* __restrict__ o5) {
    size_t i = (size_t)blockIdx.x * 256 + threadIdx.x;
    const float* in; unsigned short* out;
    if      (i < S0)                  { in = i0; out = o0; }
    else if (i < S0+S1)               { in = i1; out = o1; i -= S0; }
    else if (i < S0+S1+S2)            { in = i2; out = o2; i -= S0+S1; }
    else if (i < S0+S1+S2+S3)         { in = i3; out = o3; i -= S0+S1+S2; }
    else if (i < S0+S1+S2+S3+S4)      { in = i4; out = o4; i -= S0+S1+S2+S3; }
    else                              { in = i5; out = o5; i -= S0+S1+S2+S3+S4; }
    float4 a = ld4(in + i * 8), b = ld4(in + i * 8 + 4);
    short8 t;
    t[0] = (short)f2b(a.x); t[1] = (short)f2b(a.y); t[2] = (short)f2b(a.z); t[3] = (short)f2b(a.w);
    t[4] = (short)f2b(b.x); t[5] = (short)f2b(b.y); t[6] = (short)f2b(b.z); t[7] = (short)f2b(b.w);
    *(short8*)(out + i * 8) = t;
}

// =====================================================================
// Pure-bf16 MFMA GEMM, 128x128 tile, BK=32, 4 waves, 3-buffer LDS
// pipeline with counted vmcnt + raw s_barrier (round-8 proven).
// NEW: XOR bank-swizzle (T2) — LDS slot (row, c) holds global chunk
// c ^ swz(row), swz(row) = (row&3)^((row>>2)&3); achieved by permuting
// the per-lane GLOBAL source chunk (gload_lds dest stays linear) and
// XORing fq on the fragment read.  8-way -> 2-way bank conflict.
// C = A[M,K] @ W[N,K]^T.  MODE as in round 7.
// =====================================================================
template <int MODE>
__global__ __launch_bounds__(256) void gemm_bf16(
        const unsigned short* __restrict__ A, int lda,
        const unsigned short* __restrict__ W, const unsigned short* __restrict__ W2,
        float* __restrict__ Cf, int ldc,
        unsigned short* __restrict__ O1, unsigned short* __restrict__ O2,
        const float* __restrict__ cosb, const float* __restrict__ sinb,
        int K) {
    __shared__ unsigned short As[3][128 * 32];   // 3 x 8KB
    __shared__ unsigned short Bs[3][128 * 32];

    const int tid = threadIdx.x;
    const int bm = blockIdx.y * 128, bn = blockIdx.x * 128;
    const int w = tid >> 6, lane = tid & 63;
    const int wr = (w >> 1) * 64, wc = (w & 1) * 64;
    const int fr = lane & 15, fq = lane >> 4;

    // staging coords: wave w stages rows w*32..+31 (two 16-row chunks).
    // lane l -> tile row lr = l>>2; source chunk = (l&3) ^ swz(lr).
    const int lr = lane >> 2;
    const int swzw = (lr & 3) ^ ((lr >> 2) & 3);
    const int r0 = w * 32 + lr;
    const int c0 = (((lane & 3) ^ swzw)) * 8;

    const unsigned short* Ag0;
    if constexpr (MODE == 4) {
        Ag0 = A + (size_t)((bm >> 7) * 256 + 128 + r0) * lda + c0;   // v-feature remap
    } else {
        Ag0 = A + (size_t)(bm + r0) * lda + c0;
    }
    const unsigned short* Ag1 = Ag0 + (size_t)16 * lda;

    const unsigned short* Wg0;
    const unsigned short* Wg1;
    if constexpr (MODE == 1) {
        if (bn < 1536) {
            Wg0 = W + (size_t)(bn + r0) * K + c0;
            Wg1 = Wg0 + (size_t)16 * K;
        } else {
            int br0 = bn - 1536 + r0;      if (br0 > 575) br0 = 575;
            int br1 = bn - 1536 + r0 + 16; if (br1 > 575) br1 = 575;
            Wg0 = W2 + (size_t)br0 * K + c0;
            Wg1 = W2 + (size_t)br1 * K + c0;
        }
    } else if constexpr (MODE == 3) {
        Wg0 = W + (size_t)((bn >> 7) * 256 + r0) * K + c0;           // k_nope remap
        Wg1 = Wg0 + (size_t)16 * K;
    } else {
        Wg0 = W + (size_t)(bn + r0) * K + c0;
        Wg1 = Wg0 + (size_t)16 * K;
    }

#define STAGE(buf, koff) do { \
        gload16(Ag0 + (koff), &As[buf][(w * 32) * 32]); \
        gload16(Ag1 + (koff), &As[buf][(w * 32 + 16) * 32]); \
        gload16(Wg0 + (koff), &Bs[buf][(w * 32) * 32]); \
        gload16(Wg1 + (koff), &Bs[buf][(w * 32 + 16) * 32]); \
    } while (0)

    f32x4 acc[4][4];
    #pragma unroll
    for (int m = 0; m < 4; m++)
        #pragma unroll
        for (int n = 0; n < 4; n++) acc[m][n] = (f32x4)0.0f;

    // read-side swizzle: rows read are wr/wc + m*16 + fr -> low bits = fr
    const int swzr = (fr & 3) ^ ((fr >> 2) & 3);
    const int fqs = (fq ^ swzr) * 8;

    const int NT = K >> 5;
    STAGE(0, 0);
    STAGE(1, 32);
    int cb = 0;
    for (int t = 0; t < NT; t++) {
        // wait for tile t's 4 loads (allow the newest 4 = tile t+1's to fly)
        if (t == NT - 1) asm volatile("s_waitcnt vmcnt(0)" ::: "memory");
        else             asm volatile("s_waitcnt vmcnt(4)" ::: "memory");
        __builtin_amdgcn_s_barrier();
        __builtin_amdgcn_sched_barrier(0);

        if (t + 2 < NT) {
            int nb = cb + 2; if (nb >= 3) nb -= 3;
            STAGE(nb, (t + 2) * 32);
        }

        short8 af[4], bfr[4];
        #pragma unroll
        for (int m = 0; m < 4; m++)
            af[m] = *(const short8*)&As[cb][(wr + m * 16 + fr) * 32 + fqs];
        #pragma unroll
        for (int n = 0; n < 4; n++)
            bfr[n] = *(const short8*)&Bs[cb][(wc + n * 16 + fr) * 32 + fqs];
        #pragma unroll
        for (int m = 0; m < 4; m++)
            #pragma unroll
            for (int n = 0; n < 4; n++)
                acc[m][n] = __builtin_amdgcn_mfma_f32_16x16x32_bf16(af[m], bfr[n], acc[m][n], 0, 0, 0);

        cb++; if (cb >= 3) cb = 0;
    }
#undef STAGE

    // C/D layout: col = wc + n*16 + fr, row = wr + m*16 + fq*4 + j   [m89-verified]
    if constexpr (MODE == 0) {
        #pragma unroll
        for (int m = 0; m < 4; m++)
            #pragma unroll
            for (int n = 0; n < 4; n++) {
                const int col = bn + wc + n * 16 + fr;
                #pragma unroll
                for (int j = 0; j < 4; j++)
                    Cf[(size_t)(bm + wr + m * 16 + fq * 4 + j) * ldc + col] = acc[m][n][j];
            }
    } else if constexpr (MODE == 1) {
        #pragma unroll
        for (int m = 0; m < 4; m++)
            #pragma unroll
            for (int n = 0; n < 4; n++) {
                const int col = bn + wc + n * 16 + fr;
                if (col < 2112) {
                    #pragma unroll
                    for (int j = 0; j < 4; j++)
                        Cf[(size_t)(bm + wr + m * 16 + fq * 4 + j) * 2112 + col] = acc[m][n][j];
                }
            }
    } else if constexpr (MODE == 2) {
        #pragma unroll
        for (int n = 0; n < 4; n++) {
            const int col = bn + wc + n * 16 + fr;    // 0..3071
            const int h = col / DQK, d = col % DQK;
            #pragma unroll
            for (int m = 0; m < 4; m++) {
                #pragma unroll
                for (int j = 0; j < 4; j++) {
                    const int row = bm + wr + m * 16 + fq * 4 + j;
                    const int s = row & (SEQ - 1), b = row >> 11;
                    float v = acc[m][n][j];
                    if (d >= DVDIM) {
                        const int j5 = d - DVDIM;                 // 0..63
                        const float partner = acc[m][n ^ 2][j];   // col ^ 32, same head
                        const float rot = (j5 < 32) ? -partner : partner;
                        v = v * cosb[s * 64 + j5] + rot * sinb[s * 64 + j5];
                    }
                    O1[((size_t)(b * NHEADS + h) * SEQ + s) * DQK + d] = f2b(v);
                }
            }
        }
    } else if constexpr (MODE == 3) {
        #pragma unroll
        for (int n = 0; n < 4; n++) {
            const int col = bn + wc + n * 16 + fr;    // 0..2047 (k_nope features)
            const int h = col >> 7, d = col & 127;
            #pragma unroll
            for (int m = 0; m < 4; m++) {
                #pragma unroll
                for (int j = 0; j < 4; j++) {
                    const int row = bm + wr + m * 16 + fq * 4 + j;
                    const int s = row & (SEQ - 1);
                    const int bh = (row >> 11) * NHEADS + h;
                    O1[((size_t)bh * SEQ + s) * DQK + d] = f2b(acc[m][n][j]);
                }
            }
        }
    } else {  // MODE 4: V^T
        #pragma unroll
        for (int n = 0; n < 4; n++) {
            const int col = bn + wc + n * 16 + fr;    // 0..4095 (s rows)
            const int b = col >> 11, s = col & (SEQ - 1);
            #pragma unroll
            for (int m = 0; m < 4; m++) {
                #pragma unroll
                for (int j = 0; j < 4; j++) {
                    const int vf = bm + wr + m * 16 + fq * 4 + j;   // 0..2047
                    const int h = vf >> 7, dv = vf & 127;
                    O2[((size_t)(b * NHEADS + h) * DVDIM + dv) * SEQ + s] = f2b(acc[m][n][j]);
                }
            }
        }
    }
}

// ---------------- RMSNorm: fp32 in (row stride instride) -> bf16 out (tight) ----
__global__ __launch_bounds__(256) void rmsnorm_bf(const float* __restrict__ x,
                                                  const float* __restrict__ w,
                                                  unsigned short* __restrict__ o,
                                                  int ncols, int instride) {
    const float* xr = x + (size_t)blockIdx.x * instride;
    unsigned short* orow = o + (size_t)blockIdx.x * ncols;
    const int tid = threadIdx.x;
    float ss = 0.f;
    for (int c = tid * 4; c < ncols; c += 1024) {
        float4 v = ld4(xr + c);
        ss += v.x * v.x + v.y * v.y + v.z * v.z + v.w * v.w;
    }
    #pragma unroll
    for (int d = 32; d > 0; d >>= 1) ss += __shfl_down(ss, d);
    __shared__ float wsum[4];
    if ((tid & 63) == 0) wsum[tid >> 6] = ss;
    __syncthreads();
    float total = wsum[0] + wsum[1] + wsum[2] + wsum[3];
    float scale = 1.0f / sqrtf(total / (float)ncols + 1e-6f);
    for (int c = tid * 4; c < ncols; c += 1024) {
        float4 v = ld4(xr + c);
        short4v t;
        t[0] = (short)f2b(v.x * scale * w[c + 0]);
        t[1] = (short)f2b(v.y * scale * w[c + 1]);
        t[2] = (short)f2b(v.z * scale * w[c + 2]);
        t[3] = (short)f2b(v.w * scale * w[c + 3]);
        *(short4v*)&orow[c] = t;
    }
}

// ---------------- RoPE cos/sin table (SEQ x 64) ----------
__global__ void rope_table(float* __restrict__ cost, float* __restrict__ sint) {
    int s = blockIdx.x, j = threadIdx.x;
    int i = j & 31;
    float inv = 1.0f / powf(10000.0f, (float)i * (1.0f / 32.0f));
    float ang = (float)s * inv;
    cost[s * 64 + j] = cosf(ang);
    sint[s * 64 + j] = sinf(ang);
}

// ---------------- k_rope: rope(qkva cols 2048..2111) -> kbf[..][128..191], bcast 16 heads
__global__ void rope_k_bcast(const float* __restrict__ qkva,
                             const float* __restrict__ cost,
                             const float* __restrict__ sint,
                             unsigned short* __restrict__ kbf) {
    const int r = blockIdx.x;        // 0..4095
    const int j = threadIdx.x;       // 0..63
    const int b = r >> 11, s = r & (SEQ - 1);
    const float* base = qkva + (size_t)r * 2112 + 2048;
    const float x = base[j];
    const float rot = (j < 32) ? -base[j + 32] : base[j - 32];
    const unsigned short v = f2b(x * cost[s * 64 + j] + rot * sint[s * 64 + j]);
    #pragma unroll
    for (int h = 0; h < NHEADS; h++)
        kbf[((size_t)(b * NHEADS + h) * SEQ + s) * DQK + DVDIM + j] = v;
}

// =====================================================================
// bf16-MFMA flash attention (causal, online softmax, fp32 accum, bf16 out)
// Work-balanced pairs + reg double-buffered K/V + XCD swizzle + setprio
// + defer-max (THR=8).  (round-8 proven, unchanged)
// =====================================================================
__global__ __launch_bounds__(256, 2) void flash_mfma(const unsigned short* __restrict__ qbf,
                                                     const unsigned short* __restrict__ kbf,
                                                     const unsigned short* __restrict__ vbfT,
                                                     unsigned short* __restrict__ attn) {
    __shared__ unsigned short Ks[64][200];
    __shared__ unsigned short Vs[128][72];
    __shared__ unsigned short Ps[4][16][72];

    const int lin = blockIdx.x;
    const int xcd = lin & 7;
    const int idx = lin >> 3;                 // 0..63
    const int bh = xcd * 4 + (idx >> 4);      // 4 heads per XCD
    const int bx = idx & 15;                  // q-tile pair
    const int b = bh >> 4, h = bh & 15;
    const int tid = threadIdx.x;
    const int w = tid >> 6, lane = tid & 63;
    const int fr = lane & 15, fq = lane >> 4;

    const unsigned short* Qh = qbf + ((size_t)bh * SEQ) * DQK;
    const unsigned short* Kh = kbf + ((size_t)bh * SEQ) * DQK;
    const unsigned short* Vh = vbfT + ((size_t)bh * 128) * SEQ;

    short8 kreg[6], vreg[4];
    #pragma unroll
    for (int u = 0; u < 6; u++) {
        int i = tid + u * 256;
        int row = i / 24, c = (i % 24) * 8;
        kreg[u] = *(const short8*)(Kh + (size_t)row * DQK + c);
    }
    #pragma unroll
    for (int u = 0; u < 4; u++) {
        int i = tid + u * 256;
        int row = i >> 3, c = (i & 7) * 8;
        vreg[u] = *(const short8*)(Vh + (size_t)row * SEQ + c);
    }

    #pragma unroll 1
    for (int pass = 0; pass < 2; pass++) {
        const int qt = pass ? (NTQ - 1 - bx) : bx;
        const int q0 = qt * 64;

        short8 qf[6];
        {
            const unsigned short* qrow = Qh + (size_t)(q0 + w * 16 + fr) * DQK;
            #pragma unroll
            for (int kw = 0; kw < 6; kw++)
                qf[kw] = *(const short8*)(qrow + kw * 32 + fq * 8);
        }

        f32x4 acc[8];
        #pragma unroll
        for (int n = 0; n < 8; n++) acc[n] = (f32x4)0.0f;
        float mrow[4], lrow[4];
        #pragma unroll
        for (int j = 0; j < 4; j++) { mrow[j] = -3.0e38f; lrow[j] = 0.0f; }

        #pragma unroll 1
        for (int t = 0; t <= qt; t++) {
            __syncthreads();
            #pragma unroll
            for (int u = 0; u < 6; u++) {
                int i = tid + u * 256;
                int row = i / 24, c = (i % 24) * 8;
                *(short8*)&Ks[row][c] = kreg[u];
            }
            #pragma unroll
            for (int u = 0; u < 4; u++) {
                int i = tid + u * 256;
                int row = i >> 3, c = (i & 7) * 8;
                *(short8*)&Vs[row][c] = vreg[u];
            }
            __syncthreads();

            const int nt = (t < qt) ? (t + 1) : (pass == 0 ? 0 : -1);
            if (nt >= 0) {
                const int kt0n = nt * 64;
                #pragma unroll
                for (int u = 0; u < 6; u++) {
                    int i = tid + u * 256;
                    int row = i / 24, c = (i % 24) * 8;
                    kreg[u] = *(const short8*)(Kh + (size_t)(kt0n + row) * DQK + c);
                }
                #pragma unroll
                for (int u = 0; u < 4; u++) {
                    int i = tid + u * 256;
                    int row = i >> 3, c = (i & 7) * 8;
                    vreg[u] = *(const short8*)(Vh + (size_t)row * SEQ + kt0n + c);
                }
            }

            f32x4 sfr[4];
            #pragma unroll
            for (int n = 0; n < 4; n++) sfr[n] = (f32x4)0.0f;
            __builtin_amdgcn_s_setprio(1);
            #pragma unroll
            for (int kw = 0; kw < 6; kw++) {
                #pragma unroll
                for (int n = 0; n < 4; n++) {
                    short8 kf = *(const short8*)&Ks[n * 16 + fr][kw * 32 + fq * 8];
                    sfr[n] = __builtin_amdgcn_mfma_f32_16x16x32_bf16(qf[kw], kf, sfr[n], 0, 0, 0);
                }
            }
            __builtin_amdgcn_s_setprio(0);

            const bool diag = (t == qt);
            float pv[4][4];
            float tmax[4];
            #pragma unroll
            for (int j = 0; j < 4; j++) tmax[j] = -3.0e38f;
            #pragma unroll
            for (int n = 0; n < 4; n++) {
                #pragma unroll
                for (int j = 0; j < 4; j++) {
                    float s = sfr[n][j] * SCALING;
                    if (diag && (n * 16 + fr > w * 16 + fq * 4 + j)) s = -3.0e38f;
                    pv[n][j] = s;
                    tmax[j] = fmaxf(tmax[j], s);
                }
            }
            #pragma unroll
            for (int j = 0; j < 4; j++) {
                tmax[j] = fmaxf(tmax[j], __shfl_xor(tmax[j], 1));
                tmax[j] = fmaxf(tmax[j], __shfl_xor(tmax[j], 2));
                tmax[j] = fmaxf(tmax[j], __shfl_xor(tmax[j], 4));
                tmax[j] = fmaxf(tmax[j], __shfl_xor(tmax[j], 8));
            }
            bool defer[4];
            float mnew[4], es[4], psum[4];
            #pragma unroll
            for (int j = 0; j < 4; j++) {
                defer[j] = (tmax[j] - mrow[j] <= 8.0f);
                mnew[j] = defer[j] ? mrow[j] : tmax[j];
                es[j] = defer[j] ? 1.0f : __expf(mrow[j] - mnew[j]);
                psum[j] = 0.0f;
            }
            #pragma unroll
            for (int n = 0; n < 4; n++) {
                #pragma unroll
                for (int j = 0; j < 4; j++) {
                    float p = __expf(pv[n][j] - mnew[j]);
                    pv[n][j] = p;
                    psum[j] += p;
                }
            }
            #pragma unroll
            for (int j = 0; j < 4; j++) {
                psum[j] += __shfl_xor(psum[j], 1);
                psum[j] += __shfl_xor(psum[j], 2);
                psum[j] += __shfl_xor(psum[j], 4);
                psum[j] += __shfl_xor(psum[j], 8);
                lrow[j] = lrow[j] * es[j] + psum[j];
                mrow[j] = mnew[j];
            }
            const bool needresc = !(defer[0] && defer[1] && defer[2] && defer[3]);
            if (__any(needresc)) {
                #pragma unroll
                for (int n = 0; n < 8; n++) {
                    #pragma unroll
                    for (int j = 0; j < 4; j++) acc[n][j] *= es[j];
                }
            }
            #pragma unroll
            for (int n = 0; n < 4; n++) {
                #pragma unroll
                for (int j = 0; j < 4; j++)
                    Ps[w][fq * 4 + j][n * 16 + fr] = f2b(pv[n][j]);
            }
            __builtin_amdgcn_s_setprio(1);
            #pragma unroll
            for (int tt = 0; tt < 2; tt++) {
                short8 pa = *(const short8*)&Ps[w][fr][tt * 32 + fq * 8];
                #pragma unroll
                for (int n = 0; n < 8; n++) {
                    short8 vf = *(const short8*)&Vs[n * 16 + fr][tt * 32 + fq * 8];
                    acc[n] = __builtin_amdgcn_mfma_f32_16x16x32_bf16(pa, vf, acc[n], 0, 0, 0);
                }
            }
            __builtin_amdgcn_s_setprio(0);
        }

        // epilogue: bf16 attn [row][h*128 + dv]
        #pragma unroll
        for (int j = 0; j < 4; j++) {
            const float inv = 1.0f / lrow[j];
            unsigned short* orow = attn + (size_t)(b * SEQ + q0 + w * 16 + fq * 4 + j) * (NHEADS * DVDIM) + h * DVDIM;
            #pragma unroll
            for (int n = 0; n < 8; n++)
                orow[n * 16 + fr] = f2b(acc[n][j] * inv);
        }
    }
}

extern "C" void kernel_launch(void* const* d_in, const int* in_sizes, int n_in,
                              void* d_out, int out_size, void* d_ws, size_t ws_size,
                              hipStream_t stream) {
    const float* hidden   = (const float*)d_in[0];
    const float* q_a_w    = (const float*)d_in[1];
    const float* q_a_ln_w = (const float*)d_in[2];
    const float* q_b_w    = (const float*)d_in[3];
    const float* kv_a_w   = (const float*)d_in[4];
    const float* kv_a_ln_w= (const float*)d_in[5];
    const float* kv_b_w   = (const float*)d_in[6];
    const float* o_w      = (const float*)d_in[7];
    float* out = (float*)d_out;

    char* base = (char*)d_ws;
    size_t off = 0;
    auto alloc = [&](size_t bytes) -> void* {
        void* p = base + off;
        off += (bytes + 255) & ~(size_t)255;
        return p;
    };
    float* qkva          = (float*)alloc((size_t)MROWS * 2112 * 4);            // 34.6MB
    float* cosb          = (float*)alloc((size_t)SEQ * 64 * 4);
    float* sinb          = (float*)alloc((size_t)SEQ * 64 * 4);
    unsigned short* hbf  = (unsigned short*)alloc((size_t)MROWS * HDIM * 2);       // 16.8MB
    unsigned short* w_qa = (unsigned short*)alloc((size_t)QLORA * HDIM * 2);       // 6.3MB
    unsigned short* w_qb = (unsigned short*)alloc((size_t)3072 * QLORA * 2);       // 9.4MB
    unsigned short* w_kva= (unsigned short*)alloc((size_t)576 * HDIM * 2);         // 2.4MB
    unsigned short* w_kvb= (unsigned short*)alloc((size_t)4096 * KVLORA * 2);      // 4.2MB
    unsigned short* w_o  = (unsigned short*)alloc((size_t)HDIM * 2048 * 2);        // 8.4MB
    unsigned short* qabf = (unsigned short*)alloc((size_t)MROWS * QLORA * 2);      // 12.6MB
    unsigned short* ckvbf= (unsigned short*)alloc((size_t)MROWS * KVLORA * 2);     // 4.2MB
    unsigned short* qbf  = (unsigned short*)alloc((size_t)32 * SEQ * DQK * 2);     // 25.2MB
    unsigned short* kbf  = (unsigned short*)alloc((size_t)32 * SEQ * DQK * 2);     // 25.2MB
    unsigned short* vbfT = (unsigned short*)alloc((size_t)32 * DVDIM * SEQ * 2);   // 16.8MB
    unsigned short* attnbf=(unsigned short*)alloc((size_t)MROWS * 2048 * 2);       // 16.8MB
    // total ~184MB (<= proven 186.6MB footprint)

    // fused bf16 conversions (one launch)
    cvt_all<<<11584, 256, 0, stream>>>(hidden, q_a_w, q_b_w, kv_a_w, kv_b_w, o_w,
                                       hbf, w_qa, w_qb, w_kva, w_kvb, w_o);
    rope_table<<<SEQ, 64, 0, stream>>>(cosb, sinb);

    // fused q_a | kv_a = hidden @ [q_a_w; kv_a_w].T -> fp32 qkva [4096][2112]
    gemm_bf16<1><<<dim3(17, 32), 256, 0, stream>>>(hbf, HDIM, w_qa, w_kva,
                                                   qkva, 2112, nullptr, nullptr,
                                                   nullptr, nullptr, HDIM);
    // rmsnorms -> bf16 activations
    rmsnorm_bf<<<MROWS, 256, 0, stream>>>(qkva, q_a_ln_w, qabf, QLORA, 2112);
    rmsnorm_bf<<<MROWS, 256, 0, stream>>>(qkva + 1536, kv_a_ln_w, ckvbf, KVLORA, 2112);
    // q = norm(q_a) @ q_b_w.T -> qbf (RoPE fused)
    gemm_bf16<2><<<dim3(24, 32), 256, 0, stream>>>(qabf, QLORA, w_qb, nullptr,
                                                   nullptr, 0, qbf, nullptr,
                                                   cosb, sinb, QLORA);
    // k_nope = norm(c_kv) @ kv_b_w(nope rows).T -> kbf
    gemm_bf16<3><<<dim3(16, 32), 256, 0, stream>>>(ckvbf, KVLORA, w_kvb, nullptr,
                                                   nullptr, 0, kbf, nullptr,
                                                   nullptr, nullptr, KVLORA);
    // V^T = kv_b_w(v rows) @ norm(c_kv).T -> vbfT (natively transposed output)
    gemm_bf16<4><<<dim3(32, 16), 256, 0, stream>>>(w_kvb, KVLORA, ckvbf, nullptr,
                                                   nullptr, 0, nullptr, vbfT,
                                                   nullptr, nullptr, KVLORA);
    // roped k_rope broadcast into kbf cols 128..191
    rope_k_bcast<<<MROWS, 64, 0, stream>>>(qkva, cosb, sinb, kbf);
    // flash attention -> bf16 attn
    flash_mfma<<<512, 256, 0, stream>>>(qbf, kbf, vbfT, attnbf);
    // out = attn @ o_w.T -> fp32 d_out
    gemm_bf16<0><<<dim3(16, 32), 256, 0, stream>>>(attnbf, 2048, w_o, nullptr,
                                                   out, 2048, nullptr, nullptr,
                                                   nullptr, nullptr, 2048);
}